// Round 1
// baseline (410.014 us; speedup 1.0000x reference)
//
#include <hip/hip_runtime.h>
#include <cmath>

#define D_ 128
#define B_ 256
#define P_ 64
#define R_ 32
#define NROW (B_*P_*3)   /* 49152 */
#define NBP  (B_*P_)     /* 16384 */
#define EPS_ 1e-8f

__device__ __forceinline__ float sigm(float x){ return 1.0f/(1.0f + expf(-x)); }

// ---------------- K1: per-batch prep (hts, norms, softmax denom) ----------------
__global__ void k_prep(const int* __restrict__ pair, const int* __restrict__ relset,
                       const float* __restrict__ emb, const float* __restrict__ eu,
                       const float* __restrict__ eub,
                       float* __restrict__ hts, float* __restrict__ hinv,
                       float* __restrict__ tinv, float* __restrict__ isum)
{
    const int b = blockIdx.x;
    const int lane = threadIdx.x;           // 64 threads = 1 wave
    const float* hp = emb + (size_t)pair[2*b+0]*D_;
    const float* tp = emb + (size_t)pair[2*b+1]*D_;
    float2 hv = *(const float2*)(hp + 2*lane);
    float2 tv = *(const float2*)(tp + 2*lane);
    float2 uv = *(const float2*)(eu + 2*lane);
    float dht = hv.x*tv.x + hv.y*tv.y;
    float dhh = hv.x*hv.x + hv.y*hv.y;
    float dtt = tv.x*tv.x + tv.y*tv.y;
    #pragma unroll
    for (int o = 32; o > 0; o >>= 1) {
        dht += __shfl_xor(dht, o);
        dhh += __shfl_xor(dhh, o);
        dtt += __shfl_xor(dtt, o);
    }
    float acc = 0.f;
    const float eb = eub[0];
    for (int r = 0; r < R_; ++r) {
        const float* ep = emb + (size_t)relset[b*R_+r]*D_;
        float2 ev = *(const float2*)(ep + 2*lane);
        float du = ev.x*uv.x + ev.y*uv.y;
        #pragma unroll
        for (int o = 32; o > 0; o >>= 1) du += __shfl_xor(du, o);
        acc += expf(du + eb);
    }
    if (lane == 0) {
        float hn = 1.f / fmaxf(sqrtf(dhh), EPS_);
        float tn = 1.f / fmaxf(sqrtf(dtt), EPS_);
        hts[b]  = dht*hn*tn;
        hinv[b] = hn;
        tinv[b] = tn;
        isum[b] = 1.f/acc;
    }
}

// ---------------- K2: per-(b,p) scalars s_d (sim_dist) and s_e (e_score) ----------------
__global__ void k_scal(const int* __restrict__ path, const int* __restrict__ pair,
                       const float* __restrict__ emb, const float* __restrict__ eu,
                       const float* __restrict__ eub,
                       const float* __restrict__ hts, const float* __restrict__ hinv,
                       const float* __restrict__ tinv, const float* __restrict__ isum,
                       float* __restrict__ sd, float* __restrict__ se)
{
    const int bp = blockIdx.x;
    const int b  = bp / P_;
    const int lane = threadIdx.x;           // 64 threads = 1 wave
    const float* e1 = emb + (size_t)path[3*bp+0]*D_;
    const float* e2 = emb + (size_t)path[3*bp+1]*D_;
    const float* e3 = emb + (size_t)path[3*bp+2]*D_;
    const float* hp = emb + (size_t)pair[2*b+0]*D_;
    const float* tp = emb + (size_t)pair[2*b+1]*D_;
    float2 v1 = *(const float2*)(e1 + 2*lane);
    float2 v2 = *(const float2*)(e2 + 2*lane);
    float2 v3 = *(const float2*)(e3 + 2*lane);
    float2 hv = *(const float2*)(hp + 2*lane);
    float2 tv = *(const float2*)(tp + 2*lane);
    float2 uv = *(const float2*)(eu + 2*lane);
    float d1h = v1.x*hv.x + v1.y*hv.y;
    float d1t = v1.x*tv.x + v1.y*tv.y;
    float n1  = v1.x*v1.x + v1.y*v1.y;
    float d2h = v2.x*hv.x + v2.y*hv.y;
    float d2t = v2.x*tv.x + v2.y*tv.y;
    float n2  = v2.x*v2.x + v2.y*v2.y;
    float u1 = v1.x*uv.x + v1.y*uv.y;
    float u2 = v2.x*uv.x + v2.y*uv.y;
    float u3 = v3.x*uv.x + v3.y*uv.y;
    #pragma unroll
    for (int o = 32; o > 0; o >>= 1) {
        d1h += __shfl_xor(d1h,o); d1t += __shfl_xor(d1t,o); n1 += __shfl_xor(n1,o);
        d2h += __shfl_xor(d2h,o); d2t += __shfl_xor(d2t,o); n2 += __shfl_xor(n2,o);
        u1  += __shfl_xor(u1,o);  u2  += __shfl_xor(u2,o);  u3 += __shfl_xor(u3,o);
    }
    if (lane == 0) {
        const float hi = hinv[b], ti = tinv[b], ht = hts[b], is = isum[b], eb = eub[0];
        float n1i = 1.f / fmaxf(sqrtf(n1), EPS_);
        float n2i = 1.f / fmaxf(sqrtf(n2), EPS_);
        float se1 = 0.5f*(d1h*hi + d1t*ti)*n1i;   // 0.5*(cos(h,e1)+cos(t,e1))
        float se2 = 0.5f*(d2h*hi + d2t*ti)*n2i;
        float sr0 = 0.5f*(ht  + se1);
        float sr1 = 0.5f*(se1 + se2);
        float sr2 = 0.5f*(ht  + se2);
        sd[3*bp+0] = (1.f - sr0)*0.5f;            // sim_dist
        sd[3*bp+1] = (1.f - sr1)*0.5f;
        sd[3*bp+2] = (1.f - sr2)*0.5f;
        se[3*bp+0] = expf(u1 + eb)*is;            // e_score
        se[3*bp+1] = expf(u2 + eb)*is;
        se[3*bp+2] = expf(u3 + eb)*is;
    }
}

// ---- shared GEMM helpers: W staged transposed (WsT[k][c]) with XOR swizzle ----
// store slot: c4' = (c>>2) ^ (kk&31)  -> staging writes 2-way (free), reads conflict-free
__device__ __forceinline__ void stage_w_half(const float* __restrict__ Wg,
                                             float* __restrict__ Ws,
                                             int kh, int tid)
{
    #pragma unroll
    for (int i = 0; i < 8; ++i) {
        int fidx = i*256 + tid;          // 0..2047 float4 chunks of this k-half
        int c  = fidx >> 4;              // output column 0..127
        int j4 = fidx & 15;              // float4 index along k within half
        float4 v = *(const float4*)(Wg + c*128 + kh*64 + j4*4);
        int C = c >> 2, cl = c & 3;
        int k0 = j4*4;
        Ws[(k0+0)*128 + ((C ^ ((k0+0)&31))<<2) + cl] = v.x;
        Ws[(k0+1)*128 + ((C ^ ((k0+1)&31))<<2) + cl] = v.y;
        Ws[(k0+2)*128 + ((C ^ ((k0+2)&31))<<2) + cl] = v.z;
        Ws[(k0+3)*128 + ((C ^ ((k0+3)&31))<<2) + cl] = v.w;
    }
}

template<int NR>
__device__ __forceinline__ void gemm_khalf(const float* __restrict__ As,
                                           const float* __restrict__ Ws,
                                           int kh, int r0, int tx, float4* acc)
{
    #pragma unroll 2
    for (int kk4 = 0; kk4 < 16; ++kk4) {
        float4 a[NR];
        #pragma unroll
        for (int i = 0; i < NR; ++i)
            a[i] = *(const float4*)(As + (r0+i)*128 + kh*64 + kk4*4);
        #pragma unroll
        for (int q = 0; q < 4; ++q) {
            const int kk = kk4*4 + q;
            float4 w = *(const float4*)(Ws + kk*128 + ((tx ^ (kk & 31))<<2));
            #pragma unroll
            for (int i = 0; i < NR; ++i) {
                const float av = (q==0) ? a[i].x : (q==1) ? a[i].y : (q==2) ? a[i].z : a[i].w;
                acc[i].x = fmaf(av, w.x, acc[i].x);
                acc[i].y = fmaf(av, w.y, acc[i].y);
                acc[i].z = fmaf(av, w.z, acc[i].z);
                acc[i].w = fmaf(av, w.w, acc[i].w);
            }
        }
    }
}

// ---------------- K3: fused s_d*(A@Wd^T)+s_e*(A@We^T) -> cost -> (A-cost)@Wp^T ----------------
__global__ __launch_bounds__(256,2) void k_fused3(
    const int* __restrict__ path, const float* __restrict__ emb,
    const float* __restrict__ wd, const float* __restrict__ bd,
    const float* __restrict__ we, const float* __restrict__ be,
    const float* __restrict__ wp, const float* __restrict__ bp,
    const float* __restrict__ sdg, const float* __restrict__ seg,
    float* __restrict__ rel_in)
{
    __shared__ float As[64*128];
    __shared__ float Ws[64*128];
    __shared__ float sdS[64], seS[64];
    __shared__ int   pS[64];
    const int tid = threadIdx.x;
    const int tx = tid & 31, ty = tid >> 5;
    const int c0 = tx*4, r0 = ty*8;            // micro-tile: 8 rows x 4 cols
    const int base = blockIdx.x * 64;

    if (tid < 64) {
        pS[tid]  = path[base + tid];
        sdS[tid] = sdg[base + tid];
        seS[tid] = seg[base + tid];
    }
    __syncthreads();
    #pragma unroll
    for (int i = 0; i < 8; ++i) {
        int fidx = i*256 + tid;
        int row = fidx >> 5, c4 = fidx & 31;
        *(float4*)(As + row*128 + c4*4) =
            *(const float4*)(emb + (size_t)pS[row]*128 + c4*4);
    }

    float4 acc1[8], acc2[8];
    #pragma unroll
    for (int i = 0; i < 8; ++i) { acc1[i] = make_float4(0.f,0.f,0.f,0.f); acc2[i] = make_float4(0.f,0.f,0.f,0.f); }

    stage_w_half(wd, Ws, 0, tid); __syncthreads();
    gemm_khalf<8>(As, Ws, 0, r0, tx, acc1); __syncthreads();
    stage_w_half(wd, Ws, 1, tid); __syncthreads();
    gemm_khalf<8>(As, Ws, 1, r0, tx, acc1); __syncthreads();
    stage_w_half(we, Ws, 0, tid); __syncthreads();
    gemm_khalf<8>(As, Ws, 0, r0, tx, acc2); __syncthreads();
    stage_w_half(we, Ws, 1, tid); __syncthreads();
    gemm_khalf<8>(As, Ws, 1, r0, tx, acc2); __syncthreads();

    const float4 bd4 = *(const float4*)(bd + c0);
    const float4 be4 = *(const float4*)(be + c0);
    #pragma unroll
    for (int i = 0; i < 8; ++i) {
        const int row = r0 + i;
        float4 av = *(const float4*)(As + row*128 + c0);
        const float s_d = sdS[row], s_e = seS[row];
        float4 x;
        x.x = av.x - 1e-3f*fmaxf(s_d*acc1[i].x + s_e*acc2[i].x + bd4.x + be4.x, 0.f);
        x.y = av.y - 1e-3f*fmaxf(s_d*acc1[i].y + s_e*acc2[i].y + bd4.y + be4.y, 0.f);
        x.z = av.z - 1e-3f*fmaxf(s_d*acc1[i].z + s_e*acc2[i].z + bd4.z + be4.z, 0.f);
        x.w = av.w - 1e-3f*fmaxf(s_d*acc1[i].w + s_e*acc2[i].w + bd4.w + be4.w, 0.f);
        *(float4*)(As + row*128 + c0) = x;    // in-place: each (row,col) owned by one thread
    }
    #pragma unroll
    for (int i = 0; i < 8; ++i) acc1[i] = make_float4(0.f,0.f,0.f,0.f);
    stage_w_half(wp, Ws, 0, tid); __syncthreads();   // sync also publishes x-writes
    gemm_khalf<8>(As, Ws, 0, r0, tx, acc1); __syncthreads();
    stage_w_half(wp, Ws, 1, tid); __syncthreads();
    gemm_khalf<8>(As, Ws, 1, r0, tx, acc1);

    const float4 bp4 = *(const float4*)(bp + c0);
    #pragma unroll
    for (int i = 0; i < 8; ++i) {
        float4 o;
        o.x = acc1[i].x + bp4.x; o.y = acc1[i].y + bp4.y;
        o.z = acc1[i].z + bp4.z; o.w = acc1[i].w + bp4.w;
        *(float4*)(rel_in + (size_t)(base + r0 + i)*128 + c0) = o;
    }
}

// ---------------- K4: GRU, 3 sequential steps ----------------
__device__ __forceinline__ void gate_accum(const float* __restrict__ Xs,
                                           const float* __restrict__ Hs,
                                           float* __restrict__ Ws,
                                           const float* __restrict__ wih,
                                           const float* __restrict__ whh,
                                           int g, int tid, int r0, int tx,
                                           float4 accI[4], float4 accH[4])
{
    #pragma unroll
    for (int i=0;i<4;++i){ accI[i]=make_float4(0.f,0.f,0.f,0.f); accH[i]=make_float4(0.f,0.f,0.f,0.f); }
    const float* wi = wih + g*16384;
    const float* wh = whh + g*16384;
    stage_w_half(wi, Ws, 0, tid); __syncthreads();
    gemm_khalf<4>(Xs, Ws, 0, r0, tx, accI); __syncthreads();
    stage_w_half(wi, Ws, 1, tid); __syncthreads();
    gemm_khalf<4>(Xs, Ws, 1, r0, tx, accI); __syncthreads();
    stage_w_half(wh, Ws, 0, tid); __syncthreads();
    gemm_khalf<4>(Hs, Ws, 0, r0, tx, accH); __syncthreads();
    stage_w_half(wh, Ws, 1, tid); __syncthreads();
    gemm_khalf<4>(Hs, Ws, 1, r0, tx, accH); __syncthreads();
}

__global__ __launch_bounds__(256,2) void k_gru(
    const float* __restrict__ rel_in,
    const float* __restrict__ wih, const float* __restrict__ whh,
    const float* __restrict__ bih, const float* __restrict__ bhh,
    float* __restrict__ out)
{
    __shared__ float Xs[32*128];
    __shared__ float Hs[32*128];
    __shared__ float Ws[64*128];
    const int tid = threadIdx.x;
    const int tx = tid & 31, ty = tid >> 5;
    const int c0 = tx*4, r0 = ty*4;            // micro-tile: 4 rows x 4 cols
    const int n0 = blockIdx.x * 32;

    #pragma unroll
    for (int i = 0; i < 4; ++i) {
        int fidx = i*256 + tid;
        *(float4*)(Hs + fidx*4) = make_float4(0.f,0.f,0.f,0.f);
    }
    float4 hold[4];
    #pragma unroll
    for (int i = 0; i < 4; ++i) hold[i] = make_float4(0.f,0.f,0.f,0.f);

    for (int t = 0; t < 3; ++t) {
        #pragma unroll
        for (int i = 0; i < 4; ++i) {
            int fidx = i*256 + tid;
            int row = fidx >> 5, c4 = fidx & 31;
            *(float4*)(Xs + row*128 + c4*4) =
                *(const float4*)(rel_in + ((size_t)(n0+row)*3 + t)*128 + c4*4);
        }
        __syncthreads();   // publishes Xs (and Hs on first iteration)

        float4 accI[4], accH[4], rG[4], zG[4];
        // gate r
        gate_accum(Xs, Hs, Ws, wih, whh, 0, tid, r0, tx, accI, accH);
        {
            const float4 bi = *(const float4*)(bih + c0);
            const float4 bh = *(const float4*)(bhh + c0);
            #pragma unroll
            for (int i=0;i<4;++i){
                rG[i].x = sigm(accI[i].x+accH[i].x+bi.x+bh.x);
                rG[i].y = sigm(accI[i].y+accH[i].y+bi.y+bh.y);
                rG[i].z = sigm(accI[i].z+accH[i].z+bi.z+bh.z);
                rG[i].w = sigm(accI[i].w+accH[i].w+bi.w+bh.w);
            }
        }
        // gate z
        gate_accum(Xs, Hs, Ws, wih, whh, 1, tid, r0, tx, accI, accH);
        {
            const float4 bi = *(const float4*)(bih + 128 + c0);
            const float4 bh = *(const float4*)(bhh + 128 + c0);
            #pragma unroll
            for (int i=0;i<4;++i){
                zG[i].x = sigm(accI[i].x+accH[i].x+bi.x+bh.x);
                zG[i].y = sigm(accI[i].y+accH[i].y+bi.y+bh.y);
                zG[i].z = sigm(accI[i].z+accH[i].z+bi.z+bh.z);
                zG[i].w = sigm(accI[i].w+accH[i].w+bi.w+bh.w);
            }
        }
        // gate n + state update
        gate_accum(Xs, Hs, Ws, wih, whh, 2, tid, r0, tx, accI, accH);
        {
            const float4 bi = *(const float4*)(bih + 256 + c0);
            const float4 bh = *(const float4*)(bhh + 256 + c0);
            #pragma unroll
            for (int i=0;i<4;++i){
                float nx = tanhf(accI[i].x + bi.x + rG[i].x*(accH[i].x + bh.x));
                float ny = tanhf(accI[i].y + bi.y + rG[i].y*(accH[i].y + bh.y));
                float nz = tanhf(accI[i].z + bi.z + rG[i].z*(accH[i].z + bh.z));
                float nw = tanhf(accI[i].w + bi.w + rG[i].w*(accH[i].w + bh.w));
                hold[i].x = (1.f - zG[i].x)*nx + zG[i].x*hold[i].x;
                hold[i].y = (1.f - zG[i].y)*ny + zG[i].y*hold[i].y;
                hold[i].z = (1.f - zG[i].z)*nz + zG[i].z*hold[i].z;
                hold[i].w = (1.f - zG[i].w)*nw + zG[i].w*hold[i].w;
            }
        }
        #pragma unroll
        for (int i=0;i<4;++i)
            *(float4*)(Hs + (r0+i)*128 + c0) = hold[i];
        __syncthreads();
    }
    #pragma unroll
    for (int i=0;i<4;++i)
        *(float4*)(out + (size_t)(n0 + r0 + i)*128 + c0) = hold[i];
}

extern "C" void kernel_launch(void* const* d_in, const int* in_sizes, int n_in,
                              void* d_out, int out_size, void* d_ws, size_t ws_size,
                              hipStream_t stream)
{
    const int*   path   = (const int*)d_in[0];
    const int*   pair   = (const int*)d_in[1];
    const int*   relset = (const int*)d_in[2];
    const float* emb    = (const float*)d_in[3];
    const float* wd     = (const float*)d_in[4];
    const float* bd     = (const float*)d_in[5];
    const float* we     = (const float*)d_in[6];
    const float* be     = (const float*)d_in[7];
    const float* wp     = (const float*)d_in[8];
    const float* bp     = (const float*)d_in[9];
    const float* eu     = (const float*)d_in[10];
    const float* eub    = (const float*)d_in[11];
    const float* wih    = (const float*)d_in[12];
    const float* whh    = (const float*)d_in[13];
    const float* bih    = (const float*)d_in[14];
    const float* bhh    = (const float*)d_in[15];
    float* out = (float*)d_out;
    float* ws  = (float*)d_ws;

    // workspace layout (floats): needs ~25.6 MB
    float* hts    = ws;            // 256
    float* hinv   = ws + 256;      // 256
    float* tinv   = ws + 512;      // 256
    float* isum   = ws + 768;      // 256
    float* sdg    = ws + 1024;     // 49152
    float* seg    = sdg + NROW;    // 49152
    float* rel_in = seg + NROW;    // 49152*128

    k_prep <<<B_,   64, 0, stream>>>(pair, relset, emb, eu, eub, hts, hinv, tinv, isum);
    k_scal <<<NBP,  64, 0, stream>>>(path, pair, emb, eu, eub, hts, hinv, tinv, isum, sdg, seg);
    k_fused3<<<NROW/64, 256, 0, stream>>>(path, emb, wd, bd, we, be, wp, bp, sdg, seg, rel_in);
    k_gru  <<<NBP/32, 256, 0, stream>>>(rel_in, wih, whh, bih, bhh, out);
}

// Round 3
// 318.714 us; speedup vs baseline: 1.2865x; 1.2865x over previous
//
#include <hip/hip_runtime.h>
#include <cmath>

#define D_ 128
#define B_ 256
#define P_ 64
#define R_ 32
#define NROW (B_*P_*3)   /* 49152 */
#define NBP  (B_*P_)     /* 16384 */
#define EPS_ 1e-8f

typedef unsigned short u16;
typedef unsigned int   u32;
using bf16x8 = __attribute__((ext_vector_type(8))) __bf16;
using f32x4  = __attribute__((ext_vector_type(4))) float;

__device__ __forceinline__ float sigm(float x){ return 1.0f/(1.0f + expf(-x)); }

__device__ __forceinline__ u16 f2b(float f){         // fp32 -> bf16 RNE
    u32 u = __builtin_bit_cast(u32, f);
    u += 0x7fffu + ((u >> 16) & 1u);
    return (u16)(u >> 16);
}
__device__ __forceinline__ float b2f(u16 s){
    return __builtin_bit_cast(float, ((u32)s) << 16);
}
__device__ __forceinline__ bf16x8 pack8(float a0,float a1,float a2,float a3,
                                        float a4,float a5,float a6,float a7){
    uint4 r;
    r.x = (u32)f2b(a0) | ((u32)f2b(a1) << 16);
    r.y = (u32)f2b(a2) | ((u32)f2b(a3) << 16);
    r.z = (u32)f2b(a4) | ((u32)f2b(a5) << 16);
    r.w = (u32)f2b(a6) | ((u32)f2b(a7) << 16);
    return __builtin_bit_cast(bf16x8, r);
}

// ---------------- K1: per-batch prep ----------------
__global__ void k_prep(const int* __restrict__ pair, const int* __restrict__ relset,
                       const float* __restrict__ emb, const float* __restrict__ eu,
                       const float* __restrict__ eub,
                       float* __restrict__ hts, float* __restrict__ hinv,
                       float* __restrict__ tinv, float* __restrict__ isum)
{
    const int b = blockIdx.x;
    const int lane = threadIdx.x;
    const float* hp = emb + (size_t)pair[2*b+0]*D_;
    const float* tp = emb + (size_t)pair[2*b+1]*D_;
    float2 hv = *(const float2*)(hp + 2*lane);
    float2 tv = *(const float2*)(tp + 2*lane);
    float2 uv = *(const float2*)(eu + 2*lane);
    float dht = hv.x*tv.x + hv.y*tv.y;
    float dhh = hv.x*hv.x + hv.y*hv.y;
    float dtt = tv.x*tv.x + tv.y*tv.y;
    #pragma unroll
    for (int o = 32; o > 0; o >>= 1) {
        dht += __shfl_xor(dht, o);
        dhh += __shfl_xor(dhh, o);
        dtt += __shfl_xor(dtt, o);
    }
    float acc = 0.f;
    const float eb = eub[0];
    for (int r = 0; r < R_; ++r) {
        const float* ep = emb + (size_t)relset[b*R_+r]*D_;
        float2 ev = *(const float2*)(ep + 2*lane);
        float du = ev.x*uv.x + ev.y*uv.y;
        #pragma unroll
        for (int o = 32; o > 0; o >>= 1) du += __shfl_xor(du, o);
        acc += expf(du + eb);
    }
    if (lane == 0) {
        float hn = 1.f / fmaxf(sqrtf(dhh), EPS_);
        float tn = 1.f / fmaxf(sqrtf(dtt), EPS_);
        hts[b]  = dht*hn*tn;
        hinv[b] = hn;
        tinv[b] = tn;
        isum[b] = 1.f/acc;
    }
}

// ---------------- K2: per-(b,p) scalars ----------------
__global__ void k_scal(const int* __restrict__ path, const int* __restrict__ pair,
                       const float* __restrict__ emb, const float* __restrict__ eu,
                       const float* __restrict__ eub,
                       const float* __restrict__ hts, const float* __restrict__ hinv,
                       const float* __restrict__ tinv, const float* __restrict__ isum,
                       float* __restrict__ sd, float* __restrict__ se)
{
    const int bp = blockIdx.x;
    const int b  = bp / P_;
    const int lane = threadIdx.x;
    const float* e1 = emb + (size_t)path[3*bp+0]*D_;
    const float* e2 = emb + (size_t)path[3*bp+1]*D_;
    const float* e3 = emb + (size_t)path[3*bp+2]*D_;
    const float* hp = emb + (size_t)pair[2*b+0]*D_;
    const float* tp = emb + (size_t)pair[2*b+1]*D_;
    float2 v1 = *(const float2*)(e1 + 2*lane);
    float2 v2 = *(const float2*)(e2 + 2*lane);
    float2 v3 = *(const float2*)(e3 + 2*lane);
    float2 hv = *(const float2*)(hp + 2*lane);
    float2 tv = *(const float2*)(tp + 2*lane);
    float2 uv = *(const float2*)(eu + 2*lane);
    float d1h = v1.x*hv.x + v1.y*hv.y;
    float d1t = v1.x*tv.x + v1.y*tv.y;
    float n1  = v1.x*v1.x + v1.y*v1.y;
    float d2h = v2.x*hv.x + v2.y*hv.y;
    float d2t = v2.x*tv.x + v2.y*tv.y;
    float n2  = v2.x*v2.x + v2.y*v2.y;
    float u1 = v1.x*uv.x + v1.y*uv.y;
    float u2 = v2.x*uv.x + v2.y*uv.y;
    float u3 = v3.x*uv.x + v3.y*uv.y;
    #pragma unroll
    for (int o = 32; o > 0; o >>= 1) {
        d1h += __shfl_xor(d1h,o); d1t += __shfl_xor(d1t,o); n1 += __shfl_xor(n1,o);
        d2h += __shfl_xor(d2h,o); d2t += __shfl_xor(d2t,o); n2 += __shfl_xor(n2,o);
        u1  += __shfl_xor(u1,o);  u2  += __shfl_xor(u2,o);  u3 += __shfl_xor(u3,o);
    }
    if (lane == 0) {
        const float hi = hinv[b], ti = tinv[b], ht = hts[b], is = isum[b], eb = eub[0];
        float n1i = 1.f / fmaxf(sqrtf(n1), EPS_);
        float n2i = 1.f / fmaxf(sqrtf(n2), EPS_);
        float se1 = 0.5f*(d1h*hi + d1t*ti)*n1i;
        float se2 = 0.5f*(d2h*hi + d2t*ti)*n2i;
        float sr0 = 0.5f*(ht  + se1);
        float sr1 = 0.5f*(se1 + se2);
        float sr2 = 0.5f*(ht  + se2);
        sd[3*bp+0] = (1.f - sr0)*0.5f;
        sd[3*bp+1] = (1.f - sr1)*0.5f;
        sd[3*bp+2] = (1.f - sr2)*0.5f;
        se[3*bp+0] = expf(u1 + eb)*is;
        se[3*bp+1] = expf(u2 + eb)*is;
        se[3*bp+2] = expf(u3 + eb)*is;
    }
}

// ---- fp32 GEMM helpers (k_fused3) ----
__device__ __forceinline__ void stage_w_half(const float* __restrict__ Wg,
                                             float* __restrict__ Ws,
                                             int kh, int tid)
{
    #pragma unroll
    for (int i = 0; i < 8; ++i) {
        int fidx = i*256 + tid;
        int c  = fidx >> 4;
        int j4 = fidx & 15;
        float4 v = *(const float4*)(Wg + c*128 + kh*64 + j4*4);
        int C = c >> 2, cl = c & 3;
        int k0 = j4*4;
        Ws[(k0+0)*128 + ((C ^ ((k0+0)&31))<<2) + cl] = v.x;
        Ws[(k0+1)*128 + ((C ^ ((k0+1)&31))<<2) + cl] = v.y;
        Ws[(k0+2)*128 + ((C ^ ((k0+2)&31))<<2) + cl] = v.z;
        Ws[(k0+3)*128 + ((C ^ ((k0+3)&31))<<2) + cl] = v.w;
    }
}

template<int NR>
__device__ __forceinline__ void gemm_khalf(const float* __restrict__ As,
                                           const float* __restrict__ Ws,
                                           int kh, int r0, int tx, float4* acc)
{
    #pragma unroll 2
    for (int kk4 = 0; kk4 < 16; ++kk4) {
        float4 a[NR];
        #pragma unroll
        for (int i = 0; i < NR; ++i)
            a[i] = *(const float4*)(As + (r0+i)*128 + kh*64 + kk4*4);
        #pragma unroll
        for (int q = 0; q < 4; ++q) {
            const int kk = kk4*4 + q;
            float4 w = *(const float4*)(Ws + kk*128 + ((tx ^ (kk & 31))<<2));
            #pragma unroll
            for (int i = 0; i < NR; ++i) {
                const float av = (q==0) ? a[i].x : (q==1) ? a[i].y : (q==2) ? a[i].z : a[i].w;
                acc[i].x = fmaf(av, w.x, acc[i].x);
                acc[i].y = fmaf(av, w.y, acc[i].y);
                acc[i].z = fmaf(av, w.z, acc[i].z);
                acc[i].w = fmaf(av, w.w, acc[i].w);
            }
        }
    }
}

// ---------------- K3: fused cost pipeline -> rel (bf16 out) ----------------
__global__ __launch_bounds__(256,2) void k_fused3(
    const int* __restrict__ path, const float* __restrict__ emb,
    const float* __restrict__ wd, const float* __restrict__ bd,
    const float* __restrict__ we, const float* __restrict__ be,
    const float* __restrict__ wp, const float* __restrict__ bp,
    const float* __restrict__ sdg, const float* __restrict__ seg,
    u16* __restrict__ rel_out)
{
    __shared__ float As[64*128];
    __shared__ float Ws[64*128];
    __shared__ float sdS[64], seS[64];
    __shared__ int   pS[64];
    const int tid = threadIdx.x;
    const int tx = tid & 31, ty = tid >> 5;
    const int c0 = tx*4, r0 = ty*8;
    const int base = blockIdx.x * 64;

    if (tid < 64) {
        pS[tid]  = path[base + tid];
        sdS[tid] = sdg[base + tid];
        seS[tid] = seg[base + tid];
    }
    __syncthreads();
    #pragma unroll
    for (int i = 0; i < 8; ++i) {
        int fidx = i*256 + tid;
        int row = fidx >> 5, c4 = fidx & 31;
        *(float4*)(As + row*128 + c4*4) =
            *(const float4*)(emb + (size_t)pS[row]*128 + c4*4);
    }

    float4 acc1[8], acc2[8];
    #pragma unroll
    for (int i = 0; i < 8; ++i) { acc1[i] = make_float4(0.f,0.f,0.f,0.f); acc2[i] = make_float4(0.f,0.f,0.f,0.f); }

    stage_w_half(wd, Ws, 0, tid); __syncthreads();
    gemm_khalf<8>(As, Ws, 0, r0, tx, acc1); __syncthreads();
    stage_w_half(wd, Ws, 1, tid); __syncthreads();
    gemm_khalf<8>(As, Ws, 1, r0, tx, acc1); __syncthreads();
    stage_w_half(we, Ws, 0, tid); __syncthreads();
    gemm_khalf<8>(As, Ws, 0, r0, tx, acc2); __syncthreads();
    stage_w_half(we, Ws, 1, tid); __syncthreads();
    gemm_khalf<8>(As, Ws, 1, r0, tx, acc2); __syncthreads();

    const float4 bd4 = *(const float4*)(bd + c0);
    const float4 be4 = *(const float4*)(be + c0);
    #pragma unroll
    for (int i = 0; i < 8; ++i) {
        const int row = r0 + i;
        float4 av = *(const float4*)(As + row*128 + c0);
        const float s_d = sdS[row], s_e = seS[row];
        float4 x;
        x.x = av.x - 1e-3f*fmaxf(s_d*acc1[i].x + s_e*acc2[i].x + bd4.x + be4.x, 0.f);
        x.y = av.y - 1e-3f*fmaxf(s_d*acc1[i].y + s_e*acc2[i].y + bd4.y + be4.y, 0.f);
        x.z = av.z - 1e-3f*fmaxf(s_d*acc1[i].z + s_e*acc2[i].z + bd4.z + be4.z, 0.f);
        x.w = av.w - 1e-3f*fmaxf(s_d*acc1[i].w + s_e*acc2[i].w + bd4.w + be4.w, 0.f);
        *(float4*)(As + row*128 + c0) = x;
    }
    #pragma unroll
    for (int i = 0; i < 8; ++i) acc1[i] = make_float4(0.f,0.f,0.f,0.f);
    stage_w_half(wp, Ws, 0, tid); __syncthreads();
    gemm_khalf<8>(As, Ws, 0, r0, tx, acc1); __syncthreads();
    stage_w_half(wp, Ws, 1, tid); __syncthreads();
    gemm_khalf<8>(As, Ws, 1, r0, tx, acc1);

    const float4 bp4 = *(const float4*)(bp + c0);
    #pragma unroll
    for (int i = 0; i < 8; ++i) {
        ushort4 o;
        o.x = f2b(acc1[i].x + bp4.x);
        o.y = f2b(acc1[i].y + bp4.y);
        o.z = f2b(acc1[i].z + bp4.z);
        o.w = f2b(acc1[i].w + bp4.w);
        *(ushort4*)(rel_out + (size_t)(base + r0 + i)*128 + c0) = o;
    }
}

// ---------------- K3b: convert GRU weights fp32 -> bf16 ----------------
__global__ void k_wcvt(const float* __restrict__ wih, const float* __restrict__ whh,
                       u16* __restrict__ wib, u16* __restrict__ whb)
{
    int i = blockIdx.x*256 + threadIdx.x;     // 0..12287
    int e = i*8;
    const float* src = (e < 49152) ? (wih + e) : (whh + e - 49152);
    u16* dst = (e < 49152) ? (wib + e) : (whb + e - 49152);
    float4 a = *(const float4*)src;
    float4 b = *(const float4*)(src + 4);
    uint4 r;
    r.x = (u32)f2b(a.x) | ((u32)f2b(a.y) << 16);
    r.y = (u32)f2b(a.z) | ((u32)f2b(a.w) << 16);
    r.z = (u32)f2b(b.x) | ((u32)f2b(b.y) << 16);
    r.w = (u32)f2b(b.z) | ((u32)f2b(b.w) << 16);
    *(uint4*)dst = r;
}

// ---- bf16 MFMA GEMM building blocks (GRU) ----
__device__ __forceinline__ void stage_w16(const u16* __restrict__ src,
                                          u16* __restrict__ Ws, int tid)
{
    #pragma unroll
    for (int i = 0; i < 8; ++i) {
        int gid = i*256 + tid;              // 2048 granules of 8 bf16
        int n = gid >> 4, g = gid & 15;
        uint4 v = *(const uint4*)(src + n*128 + g*8);
        *(uint4*)(&Ws[n*128 + ((g ^ (n & 7)) << 3)]) = v;
    }
}
__device__ __forceinline__ bf16x8 ldsB(const u16* __restrict__ Ws, int n, int g)
{
    return __builtin_bit_cast(bf16x8,
        *(const uint4*)(&Ws[n*128 + ((g ^ (n & 7)) << 3)]));
}

__device__ __forceinline__ void gemmX(const u16* __restrict__ relb, int t, int row0,
                                      const u16* __restrict__ Ws, int lrow, int lk8,
                                      int wn, f32x4 (&acc)[4][4])
{
    #pragma unroll
    for (int ks = 0; ks < 4; ++ks) {
        bf16x8 a[4], b[4];
        #pragma unroll
        for (int mt = 0; mt < 4; ++mt) {
            int row = row0 + mt*16 + lrow;
            const u16* p = relb + ((size_t)row*3 + t)*128 + ks*32 + lk8*8;
            a[mt] = __builtin_bit_cast(bf16x8, *(const uint4*)p);
        }
        #pragma unroll
        for (int nt = 0; nt < 4; ++nt)
            b[nt] = ldsB(Ws, wn*64 + nt*16 + lrow, ks*4 + lk8);
        #pragma unroll
        for (int mt = 0; mt < 4; ++mt)
            #pragma unroll
            for (int nt = 0; nt < 4; ++nt)
                acc[mt][nt] = __builtin_amdgcn_mfma_f32_16x16x32_bf16(
                    a[mt], b[nt], acc[mt][nt], 0, 0, 0);
    }
}

__device__ __forceinline__ void gemmH(const float* __restrict__ hfp, int row0,
                                      const u16* __restrict__ Ws, int lrow, int lk8,
                                      int wn, f32x4 (&acc)[4][4])
{
    #pragma unroll
    for (int ks = 0; ks < 4; ++ks) {
        bf16x8 a[4], b[4];
        #pragma unroll
        for (int mt = 0; mt < 4; ++mt) {
            int row = row0 + mt*16 + lrow;
            const float* p = hfp + (size_t)row*128 + ks*32 + lk8*8;
            float4 f0 = *(const float4*)p;
            float4 f1 = *(const float4*)(p + 4);
            a[mt] = pack8(f0.x,f0.y,f0.z,f0.w, f1.x,f1.y,f1.z,f1.w);
        }
        #pragma unroll
        for (int nt = 0; nt < 4; ++nt)
            b[nt] = ldsB(Ws, wn*64 + nt*16 + lrow, ks*4 + lk8);
        #pragma unroll
        for (int mt = 0; mt < 4; ++mt)
            #pragma unroll
            for (int nt = 0; nt < 4; ++nt)
                acc[mt][nt] = __builtin_amdgcn_mfma_f32_16x16x32_bf16(
                    a[mt], b[nt], acc[mt][nt], 0, 0, 0);
    }
}

// ---------------- K4a: r / z gate:  G = sigm(x@Wi_g^T + h@Wh_g^T + bi + bh) ----------------
__global__ __launch_bounds__(256,2) void k_gate(
    const u16* __restrict__ relb, const float* __restrict__ hfp,
    const u16* __restrict__ wib, const u16* __restrict__ whb,
    const float* __restrict__ bih, const float* __restrict__ bhh,
    u16* __restrict__ Gout, int g, int t, int first)
{
    __shared__ u16 Wi[128*128];
    __shared__ u16 Wh[128*128];
    const int tid = threadIdx.x;
    stage_w16(wib + (size_t)g*16384, Wi, tid);
    if (!first) stage_w16(whb + (size_t)g*16384, Wh, tid);
    __syncthreads();

    const int wave = tid >> 6, lane = tid & 63;
    const int wm = wave >> 1, wn = wave & 1;
    const int lrow = lane & 15, lk8 = lane >> 4;
    const int row0 = blockIdx.x*128 + wm*64;

    f32x4 acc[4][4];
    #pragma unroll
    for (int m = 0; m < 4; ++m)
        #pragma unroll
        for (int n = 0; n < 4; ++n) acc[m][n] = (f32x4){0.f,0.f,0.f,0.f};

    gemmX(relb, t, row0, Wi, lrow, lk8, wn, acc);
    if (!first) gemmH(hfp, row0, Wh, lrow, lk8, wn, acc);

    #pragma unroll
    for (int nt = 0; nt < 4; ++nt) {
        int col = wn*64 + nt*16 + lrow;
        float bv = bih[g*128 + col] + bhh[g*128 + col];
        #pragma unroll
        for (int mt = 0; mt < 4; ++mt) {
            f32x4 v = acc[mt][nt];
            #pragma unroll
            for (int r = 0; r < 4; ++r) {
                int row = row0 + mt*16 + lk8*4 + r;
                Gout[(size_t)row*128 + col] = f2b(sigm(v[r] + bv));
            }
        }
    }
}

// ---------------- K4b: G0 <- r * (h@Wh_n^T + bhh_n) ----------------
__global__ __launch_bounds__(256,2) void k_hn(
    const float* __restrict__ hfp, const u16* __restrict__ whb,
    const float* __restrict__ bhh, u16* __restrict__ G0, int first)
{
    __shared__ u16 Wh[128*128];
    const int tid = threadIdx.x;
    if (!first) { stage_w16(whb + 2*16384, Wh, tid); __syncthreads(); }

    const int wave = tid >> 6, lane = tid & 63;
    const int wm = wave >> 1, wn = wave & 1;
    const int lrow = lane & 15, lk8 = lane >> 4;
    const int row0 = blockIdx.x*128 + wm*64;

    f32x4 acc[4][4];
    #pragma unroll
    for (int m = 0; m < 4; ++m)
        #pragma unroll
        for (int n = 0; n < 4; ++n) acc[m][n] = (f32x4){0.f,0.f,0.f,0.f};

    if (!first) gemmH(hfp, row0, Wh, lrow, lk8, wn, acc);

    #pragma unroll
    for (int nt = 0; nt < 4; ++nt) {
        int col = wn*64 + nt*16 + lrow;
        float bv = bhh[256 + col];
        #pragma unroll
        for (int mt = 0; mt < 4; ++mt) {
            f32x4 v = acc[mt][nt];
            #pragma unroll
            for (int r = 0; r < 4; ++r) {
                int row = row0 + mt*16 + lk8*4 + r;
                size_t idx = (size_t)row*128 + col;
                float rg = b2f(G0[idx]);
                G0[idx] = f2b(rg * (v[r] + bv));
            }
        }
    }
}

// ---------------- K4c: i_n GEMM + combine: h' = (1-z)*tanh(i_n + r*h_n) + z*h ----------------
__global__ __launch_bounds__(256,2) void k_incomb(
    const u16* __restrict__ relb, const u16* __restrict__ wib,
    const float* __restrict__ bih,
    const u16* __restrict__ G0, const u16* __restrict__ G1,
    float* __restrict__ hfp, int t, int first)
{
    __shared__ u16 Wi[128*128];
    const int tid = threadIdx.x;
    stage_w16(wib + 2*16384, Wi, tid);
    __syncthreads();

    const int wave = tid >> 6, lane = tid & 63;
    const int wm = wave >> 1, wn = wave & 1;
    const int lrow = lane & 15, lk8 = lane >> 4;
    const int row0 = blockIdx.x*128 + wm*64;

    f32x4 acc[4][4];
    #pragma unroll
    for (int m = 0; m < 4; ++m)
        #pragma unroll
        for (int n = 0; n < 4; ++n) acc[m][n] = (f32x4){0.f,0.f,0.f,0.f};

    gemmX(relb, t, row0, Wi, lrow, lk8, wn, acc);

    #pragma unroll
    for (int nt = 0; nt < 4; ++nt) {
        int col = wn*64 + nt*16 + lrow;
        float bv = bih[256 + col];
        #pragma unroll
        for (int mt = 0; mt < 4; ++mt) {
            f32x4 v = acc[mt][nt];
            #pragma unroll
            for (int r = 0; r < 4; ++r) {
                int row = row0 + mt*16 + lk8*4 + r;
                size_t idx = (size_t)row*128 + col;
                float rhn = b2f(G0[idx]);
                float z   = b2f(G1[idx]);
                float n   = tanhf(v[r] + bv + rhn);
                float hp  = first ? 0.f : hfp[idx];
                hfp[idx] = (1.f - z)*n + z*hp;
            }
        }
    }
}

extern "C" void kernel_launch(void* const* d_in, const int* in_sizes, int n_in,
                              void* d_out, int out_size, void* d_ws, size_t ws_size,
                              hipStream_t stream)
{
    const int*   path   = (const int*)d_in[0];
    const int*   pair   = (const int*)d_in[1];
    const int*   relset = (const int*)d_in[2];
    const float* emb    = (const float*)d_in[3];
    const float* wd     = (const float*)d_in[4];
    const float* bd     = (const float*)d_in[5];
    const float* we     = (const float*)d_in[6];
    const float* be     = (const float*)d_in[7];
    const float* wp     = (const float*)d_in[8];
    const float* bp     = (const float*)d_in[9];
    const float* eu     = (const float*)d_in[10];
    const float* eub    = (const float*)d_in[11];
    const float* wih    = (const float*)d_in[12];
    const float* whh    = (const float*)d_in[13];
    const float* bih    = (const float*)d_in[14];
    const float* bhh    = (const float*)d_in[15];
    float* out = (float*)d_out;
    float* ws  = (float*)d_ws;

    // workspace layout (float offsets), total ~21.6 MB (round-1 proved >=25.5 MB OK)
    float* hts    = ws;                     // 256
    float* hinv   = ws + 256;
    float* tinv   = ws + 512;
    float* isum   = ws + 768;
    float* sdg    = ws + 1024;              // 49152
    float* seg    = sdg + NROW;             // 49152
    u16*   relb   = (u16*)(ws + 99328);     // 49152*128 bf16 = 12.58 MB -> ends 3245056
    u16*   wib    = (u16*)(ws + 3245056);   // 3*128*128 bf16 -> ends 3269632
    u16*   whb    = (u16*)(ws + 3269632);   // -> ends 3294208
    u16*   G0     = (u16*)(ws + 3294208);   // 16384*128 bf16 -> ends 4342784
    u16*   G1     = (u16*)(ws + 4342784);   // -> ends 5391360 (21.57 MB)

    k_prep  <<<B_,      64, 0, stream>>>(pair, relset, emb, eu, eub, hts, hinv, tinv, isum);
    k_scal  <<<NBP,     64, 0, stream>>>(path, pair, emb, eu, eub, hts, hinv, tinv, isum, sdg, seg);
    k_wcvt  <<<48,     256, 0, stream>>>(wih, whh, wib, whb);
    k_fused3<<<NROW/64,256, 0, stream>>>(path, emb, wd, bd, we, be, wp, bp, sdg, seg, relb);

    for (int t = 0; t < 3; ++t) {
        const int first = (t == 0);
        k_gate  <<<128, 256, 0, stream>>>(relb, out, wib, whb, bih, bhh, G0, 0, t, first);
        k_gate  <<<128, 256, 0, stream>>>(relb, out, wib, whb, bih, bhh, G1, 1, t, first);
        k_hn    <<<128, 256, 0, stream>>>(out, whb, bhh, G0, first);
        k_incomb<<<128, 256, 0, stream>>>(relb, wib, bih, G0, G1, out, t, first);
    }
}

// Round 4
// 125.266 us; speedup vs baseline: 3.2732x; 2.5443x over previous
//
#include <hip/hip_runtime.h>
#include <cmath>

#define D_ 128
#define B_ 256
#define P_ 64
#define R_ 32
#define NROW (B_*P_*3)   /* 49152 */
#define NBP  (B_*P_)     /* 16384 */
#define EPS_ 1e-8f

typedef unsigned short u16;
typedef unsigned int   u32;
using bf16x8 = __attribute__((ext_vector_type(8))) __bf16;
using f32x4  = __attribute__((ext_vector_type(4))) float;

__device__ __forceinline__ float sigm(float x){ return 1.0f/(1.0f + expf(-x)); }

__device__ __forceinline__ u16 f2b(float f){         // fp32 -> bf16 RNE
    u32 u = __builtin_bit_cast(u32, f);
    u += 0x7fffu + ((u >> 16) & 1u);
    return (u16)(u >> 16);
}
__device__ __forceinline__ float b2f(u16 s){
    return __builtin_bit_cast(float, ((u32)s) << 16);
}
__device__ __forceinline__ bf16x8 pack8(float a0,float a1,float a2,float a3,
                                        float a4,float a5,float a6,float a7){
    uint4 r;
    r.x = (u32)f2b(a0) | ((u32)f2b(a1) << 16);
    r.y = (u32)f2b(a2) | ((u32)f2b(a3) << 16);
    r.z = (u32)f2b(a4) | ((u32)f2b(a5) << 16);
    r.w = (u32)f2b(a6) | ((u32)f2b(a7) << 16);
    return __builtin_bit_cast(bf16x8, r);
}
__device__ __forceinline__ bf16x8 ldg8(const u16* p){
    return __builtin_bit_cast(bf16x8, *(const uint4*)p);
}
// swizzled LDS bf16 tile: slot(row, granule g) at row*128 + ((g^(row&7))<<3)
__device__ __forceinline__ bf16x8 ldA(const u16* Xs, int row, int gk){
    return __builtin_bit_cast(bf16x8,
        *(const uint4*)(&Xs[row*128 + ((gk ^ (row & 7)) << 3)]));
}

// ---------------- K1: per-batch prep ----------------
__global__ void k_prep(const int* __restrict__ pair, const int* __restrict__ relset,
                       const float* __restrict__ emb, const float* __restrict__ eu,
                       const float* __restrict__ eub,
                       float* __restrict__ hts, float* __restrict__ hinv,
                       float* __restrict__ tinv, float* __restrict__ isum)
{
    const int b = blockIdx.x;
    const int lane = threadIdx.x;
    const float* hp = emb + (size_t)pair[2*b+0]*D_;
    const float* tp = emb + (size_t)pair[2*b+1]*D_;
    float2 hv = *(const float2*)(hp + 2*lane);
    float2 tv = *(const float2*)(tp + 2*lane);
    float2 uv = *(const float2*)(eu + 2*lane);
    float dht = hv.x*tv.x + hv.y*tv.y;
    float dhh = hv.x*hv.x + hv.y*hv.y;
    float dtt = tv.x*tv.x + tv.y*tv.y;
    #pragma unroll
    for (int o = 32; o > 0; o >>= 1) {
        dht += __shfl_xor(dht, o);
        dhh += __shfl_xor(dhh, o);
        dtt += __shfl_xor(dtt, o);
    }
    float acc = 0.f;
    const float eb = eub[0];
    for (int r = 0; r < R_; ++r) {
        const float* ep = emb + (size_t)relset[b*R_+r]*D_;
        float2 ev = *(const float2*)(ep + 2*lane);
        float du = ev.x*uv.x + ev.y*uv.y;
        #pragma unroll
        for (int o = 32; o > 0; o >>= 1) du += __shfl_xor(du, o);
        acc += expf(du + eb);
    }
    if (lane == 0) {
        float hn = 1.f / fmaxf(sqrtf(dhh), EPS_);
        float tn = 1.f / fmaxf(sqrtf(dtt), EPS_);
        hts[b]  = dht*hn*tn;
        hinv[b] = hn;
        tinv[b] = tn;
        isum[b] = 1.f/acc;
    }
}

// ---------------- K2: per-(b,p) scalars ----------------
__global__ void k_scal(const int* __restrict__ path, const int* __restrict__ pair,
                       const float* __restrict__ emb, const float* __restrict__ eu,
                       const float* __restrict__ eub,
                       const float* __restrict__ hts, const float* __restrict__ hinv,
                       const float* __restrict__ tinv, const float* __restrict__ isum,
                       float* __restrict__ sd, float* __restrict__ se)
{
    const int bp = blockIdx.x;
    const int b  = bp / P_;
    const int lane = threadIdx.x;
    const float* e1 = emb + (size_t)path[3*bp+0]*D_;
    const float* e2 = emb + (size_t)path[3*bp+1]*D_;
    const float* e3 = emb + (size_t)path[3*bp+2]*D_;
    const float* hp = emb + (size_t)pair[2*b+0]*D_;
    const float* tp = emb + (size_t)pair[2*b+1]*D_;
    float2 v1 = *(const float2*)(e1 + 2*lane);
    float2 v2 = *(const float2*)(e2 + 2*lane);
    float2 v3 = *(const float2*)(e3 + 2*lane);
    float2 hv = *(const float2*)(hp + 2*lane);
    float2 tv = *(const float2*)(tp + 2*lane);
    float2 uv = *(const float2*)(eu + 2*lane);
    float d1h = v1.x*hv.x + v1.y*hv.y;
    float d1t = v1.x*tv.x + v1.y*tv.y;
    float n1  = v1.x*v1.x + v1.y*v1.y;
    float d2h = v2.x*hv.x + v2.y*hv.y;
    float d2t = v2.x*tv.x + v2.y*tv.y;
    float n2  = v2.x*v2.x + v2.y*v2.y;
    float u1 = v1.x*uv.x + v1.y*uv.y;
    float u2 = v2.x*uv.x + v2.y*uv.y;
    float u3 = v3.x*uv.x + v3.y*uv.y;
    #pragma unroll
    for (int o = 32; o > 0; o >>= 1) {
        d1h += __shfl_xor(d1h,o); d1t += __shfl_xor(d1t,o); n1 += __shfl_xor(n1,o);
        d2h += __shfl_xor(d2h,o); d2t += __shfl_xor(d2t,o); n2 += __shfl_xor(n2,o);
        u1  += __shfl_xor(u1,o);  u2  += __shfl_xor(u2,o);  u3 += __shfl_xor(u3,o);
    }
    if (lane == 0) {
        const float hi = hinv[b], ti = tinv[b], ht = hts[b], is = isum[b], eb = eub[0];
        float n1i = 1.f / fmaxf(sqrtf(n1), EPS_);
        float n2i = 1.f / fmaxf(sqrtf(n2), EPS_);
        float se1 = 0.5f*(d1h*hi + d1t*ti)*n1i;
        float se2 = 0.5f*(d2h*hi + d2t*ti)*n2i;
        float sr0 = 0.5f*(ht  + se1);
        float sr1 = 0.5f*(se1 + se2);
        float sr2 = 0.5f*(ht  + se2);
        sd[3*bp+0] = (1.f - sr0)*0.5f;
        sd[3*bp+1] = (1.f - sr1)*0.5f;
        sd[3*bp+2] = (1.f - sr2)*0.5f;
        se[3*bp+0] = expf(u1 + eb)*is;
        se[3*bp+1] = expf(u2 + eb)*is;
        se[3*bp+2] = expf(u3 + eb)*is;
    }
}

// ---------------- K3: convert ALL weights fp32 -> bf16 ----------------
// segments: wd[16384] we[16384] wp[16384] wih[49152] whh[49152]  (147456 total)
__global__ void k_wcvt(const float* __restrict__ wd, const float* __restrict__ we,
                       const float* __restrict__ wp, const float* __restrict__ wih,
                       const float* __restrict__ whh,
                       u16* __restrict__ wdb, u16* __restrict__ web,
                       u16* __restrict__ wpb, u16* __restrict__ wib,
                       u16* __restrict__ whb)
{
    int i = blockIdx.x*256 + threadIdx.x;     // 0..18431
    int e = i*8;
    const float* src; u16* dst; int off;
    if      (e < 16384) { src = wd;  dst = wdb; off = e; }
    else if (e < 32768) { src = we;  dst = web; off = e - 16384; }
    else if (e < 49152) { src = wp;  dst = wpb; off = e - 32768; }
    else if (e < 98304) { src = wih; dst = wib; off = e - 49152; }
    else                { src = whh; dst = whb; off = e - 98304; }
    float4 a = *(const float4*)(src + off);
    float4 b = *(const float4*)(src + off + 4);
    uint4 r;
    r.x = (u32)f2b(a.x) | ((u32)f2b(a.y) << 16);
    r.y = (u32)f2b(a.z) | ((u32)f2b(a.w) << 16);
    r.z = (u32)f2b(b.x) | ((u32)f2b(b.y) << 16);
    r.w = (u32)f2b(b.z) | ((u32)f2b(b.w) << 16);
    *(uint4*)(dst + off) = r;
}

// ---------------- K4: fused cost pipeline, MFMA bf16 ----------------
// 64 rows/block, waves 1x4 (each wave: all 64 rows x 32 cols)
// out: relb t-major [3][16384][128] bf16
__global__ __launch_bounds__(256,2) void k_cost(
    const int* __restrict__ path, const float* __restrict__ emb,
    const u16* __restrict__ wdb, const float* __restrict__ bd,
    const u16* __restrict__ web, const float* __restrict__ be,
    const u16* __restrict__ wpb, const float* __restrict__ bp,
    const float* __restrict__ sdg, const float* __restrict__ seg,
    u16* __restrict__ relb)
{
    __shared__ u16   Xs[64*128];          // 16 KB, swizzled bf16 tile
    __shared__ float sdS[64], seS[64];
    __shared__ int   pS[64];
    const int tid  = threadIdx.x;
    const int base = blockIdx.x * 64;

    if (tid < 64) {
        pS[tid]  = path[base + tid];
        sdS[tid] = sdg[base + tid];
        seS[tid] = seg[base + tid];
    }
    __syncthreads();

    // gather emb rows -> bf16 swizzled LDS
    #pragma unroll
    for (int i = 0; i < 4; ++i) {
        int gid = i*256 + tid;            // 1024 granules of 8 bf16
        int r = gid >> 4, g = gid & 15;
        const float* sp = emb + (size_t)pS[r]*128 + g*8;
        float4 f0 = *(const float4*)sp;
        float4 f1 = *(const float4*)(sp + 4);
        bf16x8 v = pack8(f0.x,f0.y,f0.z,f0.w, f1.x,f1.y,f1.z,f1.w);
        *(uint4*)(&Xs[r*128 + ((g ^ (r & 7)) << 3)]) = __builtin_bit_cast(uint4, v);
    }
    __syncthreads();

    const int wave = tid >> 6, lane = tid & 63;
    const int lrow = lane & 15, lk8 = lane >> 4;
    const int wn = wave;                  // 32-col strip

    f32x4 accD[4][2], accE[4][2];
    #pragma unroll
    for (int m = 0; m < 4; ++m)
        #pragma unroll
        for (int n = 0; n < 2; ++n) { accD[m][n] = (f32x4){0,0,0,0}; accE[m][n] = (f32x4){0,0,0,0}; }

    #pragma unroll
    for (int ks = 0; ks < 4; ++ks) {
        const int gk = ks*4 + lk8;
        bf16x8 a[4];
        #pragma unroll
        for (int mt = 0; mt < 4; ++mt) a[mt] = ldA(Xs, mt*16 + lrow, gk);
        #pragma unroll
        for (int nt = 0; nt < 2; ++nt) {
            const int n = wn*32 + nt*16 + lrow;
            bf16x8 bD = ldg8(wdb + n*128 + gk*8);
            bf16x8 bE = ldg8(web + n*128 + gk*8);
            #pragma unroll
            for (int mt = 0; mt < 4; ++mt) {
                accD[mt][nt] = __builtin_amdgcn_mfma_f32_16x16x32_bf16(a[mt], bD, accD[mt][nt], 0,0,0);
                accE[mt][nt] = __builtin_amdgcn_mfma_f32_16x16x32_bf16(a[mt], bE, accE[mt][nt], 0,0,0);
            }
        }
    }
    __syncthreads();   // all GEMM reads of Xs done

    // cost epilogue, in-place on Xs (each element owned by exactly one lane)
    #pragma unroll
    for (int nt = 0; nt < 2; ++nt) {
        const int col = wn*32 + nt*16 + lrow;
        const float bde = bd[col] + be[col];
        #pragma unroll
        for (int mt = 0; mt < 4; ++mt) {
            #pragma unroll
            for (int rr = 0; rr < 4; ++rr) {
                const int row = mt*16 + lk8*4 + rr;
                const int sl  = row*128 + (((col>>3) ^ (row&7))<<3) + (col&7);
                float relv = b2f(Xs[sl]);
                float c = sdS[row]*accD[mt][nt][rr] + seS[row]*accE[mt][nt][rr] + bde;
                Xs[sl] = f2b(relv - 1e-3f*fmaxf(c, 0.f));
            }
        }
    }
    __syncthreads();

    // x @ Wp^T
    f32x4 accP[4][2];
    #pragma unroll
    for (int m = 0; m < 4; ++m)
        #pragma unroll
        for (int n = 0; n < 2; ++n) accP[m][n] = (f32x4){0,0,0,0};
    #pragma unroll
    for (int ks = 0; ks < 4; ++ks) {
        const int gk = ks*4 + lk8;
        bf16x8 a[4];
        #pragma unroll
        for (int mt = 0; mt < 4; ++mt) a[mt] = ldA(Xs, mt*16 + lrow, gk);
        #pragma unroll
        for (int nt = 0; nt < 2; ++nt) {
            const int n = wn*32 + nt*16 + lrow;
            bf16x8 bP = ldg8(wpb + n*128 + gk*8);
            #pragma unroll
            for (int mt = 0; mt < 4; ++mt)
                accP[mt][nt] = __builtin_amdgcn_mfma_f32_16x16x32_bf16(a[mt], bP, accP[mt][nt], 0,0,0);
        }
    }

    // store rel_in bf16, t-major: relb[(grow%3)][grow/3][col]
    #pragma unroll
    for (int nt = 0; nt < 2; ++nt) {
        const int col = wn*32 + nt*16 + lrow;
        const float bpv = bp[col];
        #pragma unroll
        for (int mt = 0; mt < 4; ++mt) {
            #pragma unroll
            for (int rr = 0; rr < 4; ++rr) {
                const int row  = mt*16 + lk8*4 + rr;
                const int grow = base + row;
                const int tt   = grow - (grow/3)*3;
                const int bprow= grow/3;
                relb[((size_t)tt*NBP + bprow)*128 + col] = f2b(accP[mt][nt][rr] + bpv);
            }
        }
    }
}

// ---------------- K5: one full GRU timestep (gates + combine) ----------------
// 32 rows/block, 512 blocks, waves 1x4 (all rows x 32-col strip)
__global__ __launch_bounds__(256,2) void k_step(
    const u16* __restrict__ relb,    // [3][16384][128] bf16
    const u16* __restrict__ wib, const u16* __restrict__ whb,
    const float* __restrict__ bih, const float* __restrict__ bhh,
    float* __restrict__ hfp, int t, int first)
{
    __shared__ u16 Gs[2*32*128];      // r, z  (16 KB)
    const int tid = threadIdx.x;
    const int bp0 = blockIdx.x * 32;
    const int wave = tid >> 6, lane = tid & 63;
    const int lrow = lane & 15, lk8 = lane >> 4;
    const int wn = wave;
    const u16* xsl = relb + (size_t)t*NBP*128;

    // ---- phase 1: r, z ----
    f32x4 accR[2][2], accZ[2][2];
    #pragma unroll
    for (int m = 0; m < 2; ++m)
        #pragma unroll
        for (int n = 0; n < 2; ++n) { accR[m][n] = (f32x4){0,0,0,0}; accZ[m][n] = (f32x4){0,0,0,0}; }

    #pragma unroll
    for (int ks = 0; ks < 4; ++ks) {
        const int gk = ks*4 + lk8;
        bf16x8 ax[2];
        #pragma unroll
        for (int mt = 0; mt < 2; ++mt)
            ax[mt] = ldg8(xsl + (size_t)(bp0 + mt*16 + lrow)*128 + gk*8);
        #pragma unroll
        for (int nt = 0; nt < 2; ++nt) {
            const int n = wn*32 + nt*16 + lrow;
            bf16x8 bR = ldg8(wib + n*128 + gk*8);
            bf16x8 bZ = ldg8(wib + 16384 + n*128 + gk*8);
            #pragma unroll
            for (int mt = 0; mt < 2; ++mt) {
                accR[mt][nt] = __builtin_amdgcn_mfma_f32_16x16x32_bf16(ax[mt], bR, accR[mt][nt], 0,0,0);
                accZ[mt][nt] = __builtin_amdgcn_mfma_f32_16x16x32_bf16(ax[mt], bZ, accZ[mt][nt], 0,0,0);
            }
        }
        if (!first) {
            bf16x8 ah[2];
            #pragma unroll
            for (int mt = 0; mt < 2; ++mt) {
                const float* p = hfp + (size_t)(bp0 + mt*16 + lrow)*128 + gk*8;
                float4 f0 = *(const float4*)p;
                float4 f1 = *(const float4*)(p + 4);
                ah[mt] = pack8(f0.x,f0.y,f0.z,f0.w, f1.x,f1.y,f1.z,f1.w);
            }
            #pragma unroll
            for (int nt = 0; nt < 2; ++nt) {
                const int n = wn*32 + nt*16 + lrow;
                bf16x8 bR = ldg8(whb + n*128 + gk*8);
                bf16x8 bZ = ldg8(whb + 16384 + n*128 + gk*8);
                #pragma unroll
                for (int mt = 0; mt < 2; ++mt) {
                    accR[mt][nt] = __builtin_amdgcn_mfma_f32_16x16x32_bf16(ah[mt], bR, accR[mt][nt], 0,0,0);
                    accZ[mt][nt] = __builtin_amdgcn_mfma_f32_16x16x32_bf16(ah[mt], bZ, accZ[mt][nt], 0,0,0);
                }
            }
        }
    }
    // park r, z in LDS
    #pragma unroll
    for (int nt = 0; nt < 2; ++nt) {
        const int col = wn*32 + nt*16 + lrow;
        const float brv = bih[col]       + bhh[col];
        const float bzv = bih[128 + col] + bhh[128 + col];
        #pragma unroll
        for (int mt = 0; mt < 2; ++mt) {
            #pragma unroll
            for (int rr = 0; rr < 4; ++rr) {
                const int row = mt*16 + lk8*4 + rr;
                Gs[row*128 + col]        = f2b(sigm(accR[mt][nt][rr] + brv));
                Gs[4096 + row*128 + col] = f2b(sigm(accZ[mt][nt][rr] + bzv));
            }
        }
    }
    __syncthreads();

    // ---- phase 2: i_n, h_n ----
    f32x4 accI[2][2], accH[2][2];
    #pragma unroll
    for (int m = 0; m < 2; ++m)
        #pragma unroll
        for (int n = 0; n < 2; ++n) { accI[m][n] = (f32x4){0,0,0,0}; accH[m][n] = (f32x4){0,0,0,0}; }

    #pragma unroll
    for (int ks = 0; ks < 4; ++ks) {
        const int gk = ks*4 + lk8;
        bf16x8 ax[2];
        #pragma unroll
        for (int mt = 0; mt < 2; ++mt)
            ax[mt] = ldg8(xsl + (size_t)(bp0 + mt*16 + lrow)*128 + gk*8);
        #pragma unroll
        for (int nt = 0; nt < 2; ++nt) {
            const int n = wn*32 + nt*16 + lrow;
            bf16x8 bI = ldg8(wib + 2*16384 + n*128 + gk*8);
            #pragma unroll
            for (int mt = 0; mt < 2; ++mt)
                accI[mt][nt] = __builtin_amdgcn_mfma_f32_16x16x32_bf16(ax[mt], bI, accI[mt][nt], 0,0,0);
        }
        if (!first) {
            bf16x8 ah[2];
            #pragma unroll
            for (int mt = 0; mt < 2; ++mt) {
                const float* p = hfp + (size_t)(bp0 + mt*16 + lrow)*128 + gk*8;
                float4 f0 = *(const float4*)p;
                float4 f1 = *(const float4*)(p + 4);
                ah[mt] = pack8(f0.x,f0.y,f0.z,f0.w, f1.x,f1.y,f1.z,f1.w);
            }
            #pragma unroll
            for (int nt = 0; nt < 2; ++nt) {
                const int n = wn*32 + nt*16 + lrow;
                bf16x8 bH = ldg8(whb + 2*16384 + n*128 + gk*8);
                #pragma unroll
                for (int mt = 0; mt < 2; ++mt)
                    accH[mt][nt] = __builtin_amdgcn_mfma_f32_16x16x32_bf16(ah[mt], bH, accH[mt][nt], 0,0,0);
            }
        }
    }
    __syncthreads();   // all hfp reads done before any write

    // ---- combine ----
    #pragma unroll
    for (int nt = 0; nt < 2; ++nt) {
        const int col = wn*32 + nt*16 + lrow;
        const float biN = bih[256 + col];
        const float bhN = bhh[256 + col];
        #pragma unroll
        for (int mt = 0; mt < 2; ++mt) {
            #pragma unroll
            for (int rr = 0; rr < 4; ++rr) {
                const int row = mt*16 + lk8*4 + rr;
                const size_t idx = (size_t)(bp0 + row)*128 + col;
                float rv = b2f(Gs[row*128 + col]);
                float zv = b2f(Gs[4096 + row*128 + col]);
                float hn = accH[mt][nt][rr] + bhN;
                float nn = tanhf(accI[mt][nt][rr] + biN + rv*hn);
                float hp = first ? 0.f : hfp[idx];
                hfp[idx] = (1.f - zv)*nn + zv*hp;
            }
        }
    }
}

extern "C" void kernel_launch(void* const* d_in, const int* in_sizes, int n_in,
                              void* d_out, int out_size, void* d_ws, size_t ws_size,
                              hipStream_t stream)
{
    const int*   path   = (const int*)d_in[0];
    const int*   pair   = (const int*)d_in[1];
    const int*   relset = (const int*)d_in[2];
    const float* emb    = (const float*)d_in[3];
    const float* wd     = (const float*)d_in[4];
    const float* bd     = (const float*)d_in[5];
    const float* we     = (const float*)d_in[6];
    const float* be     = (const float*)d_in[7];
    const float* wp     = (const float*)d_in[8];
    const float* bp     = (const float*)d_in[9];
    const float* eu     = (const float*)d_in[10];
    const float* eub    = (const float*)d_in[11];
    const float* wih    = (const float*)d_in[12];
    const float* whh    = (const float*)d_in[13];
    const float* bih    = (const float*)d_in[14];
    const float* bhh    = (const float*)d_in[15];
    float* out = (float*)d_out;
    float* ws  = (float*)d_ws;

    // workspace (float offsets), total ~13.3 MB (well under proven 21.6 MB)
    float* hts    = ws;                     // 256
    float* hinv   = ws + 256;
    float* tinv   = ws + 512;
    float* isum   = ws + 768;
    float* sdg    = ws + 1024;              // 49152
    float* seg    = sdg + NROW;             // 49152 -> ends 99328
    u16*   relb   = (u16*)(ws + 99328);     // 3*16384*128 bf16 -> ends 3245056
    u16*   wdb    = (u16*)(ws + 3245056);   // 16384 u16 -> 3253248
    u16*   web    = (u16*)(ws + 3253248);   // -> 3261440
    u16*   wpb    = (u16*)(ws + 3261440);   // -> 3269632
    u16*   wib    = (u16*)(ws + 3269632);   // 49152 u16 -> 3294208
    u16*   whb    = (u16*)(ws + 3294208);   // -> 3318784  (13.28 MB)

    k_prep <<<B_,      64, 0, stream>>>(pair, relset, emb, eu, eub, hts, hinv, tinv, isum);
    k_scal <<<NBP,     64, 0, stream>>>(path, pair, emb, eu, eub, hts, hinv, tinv, isum, sdg, seg);
    k_wcvt <<<72,     256, 0, stream>>>(wd, we, wp, wih, whh, wdb, web, wpb, wib, whb);
    k_cost <<<NROW/64,256, 0, stream>>>(path, emb, wdb, bd, web, be, wpb, bp, sdg, seg, relb);

    for (int t = 0; t < 3; ++t)
        k_step<<<NBP/32, 256, 0, stream>>>(relb, wib, whb, bih, bhh, out, t, (t==0));
}

// Round 5
// 93.711 us; speedup vs baseline: 4.3753x; 1.3367x over previous
//
#include <hip/hip_runtime.h>
#include <cmath>

#define D_ 128
#define B_ 256
#define P_ 64
#define R_ 32
#define NROW (B_*P_*3)   /* 49152 */
#define NBP  (B_*P_)     /* 16384 */
#define EPS_ 1e-8f

typedef unsigned short u16;
typedef unsigned int   u32;
using bf16x8 = __attribute__((ext_vector_type(8))) __bf16;
using f32x4  = __attribute__((ext_vector_type(4))) float;

__device__ __forceinline__ float sigm(float x){ return 1.0f/(1.0f + expf(-x)); }

__device__ __forceinline__ u16 f2b(float f){         // fp32 -> bf16 RNE
    u32 u = __builtin_bit_cast(u32, f);
    u += 0x7fffu + ((u >> 16) & 1u);
    return (u16)(u >> 16);
}
__device__ __forceinline__ float b2f(u16 s){
    return __builtin_bit_cast(float, ((u32)s) << 16);
}
__device__ __forceinline__ bf16x8 pack8(float a0,float a1,float a2,float a3,
                                        float a4,float a5,float a6,float a7){
    uint4 r;
    r.x = (u32)f2b(a0) | ((u32)f2b(a1) << 16);
    r.y = (u32)f2b(a2) | ((u32)f2b(a3) << 16);
    r.z = (u32)f2b(a4) | ((u32)f2b(a5) << 16);
    r.w = (u32)f2b(a6) | ((u32)f2b(a7) << 16);
    return __builtin_bit_cast(bf16x8, r);
}
__device__ __forceinline__ bf16x8 ldg8(const u16* p){
    return __builtin_bit_cast(bf16x8, *(const uint4*)p);
}
// swizzled LDS bf16 tile: slot(row, granule g) at row*128 + ((g^(row&7))<<3)
__device__ __forceinline__ bf16x8 ldA(const u16* Xs, int row, int gk){
    return __builtin_bit_cast(bf16x8,
        *(const uint4*)(&Xs[row*128 + ((gk ^ (row & 7)) << 3)]));
}
__device__ __forceinline__ int swz_slot(int row, int col){
    return row*128 + (((col >> 3) ^ (row & 7)) << 3) + (col & 7);
}

// ---------------- K1: fused prep + scal + weight-convert ----------------
// blocks [0,256): per-batch prep + 64 p-scalars
// blocks [256,328): fp32->bf16 weight conversion
__global__ __launch_bounds__(256) void k_fuse0(
    const int* __restrict__ pair, const int* __restrict__ relset,
    const int* __restrict__ path,
    const float* __restrict__ emb, const float* __restrict__ eu,
    const float* __restrict__ eub,
    const float* __restrict__ wd, const float* __restrict__ we,
    const float* __restrict__ wp, const float* __restrict__ wih,
    const float* __restrict__ whh,
    u16* __restrict__ wdb, u16* __restrict__ web, u16* __restrict__ wpb,
    u16* __restrict__ wib, u16* __restrict__ whb,
    float* __restrict__ sd, float* __restrict__ se)
{
    const int blk = blockIdx.x;
    const int tid = threadIdx.x;

    if (blk >= B_) {           // ---- weight convert region ----
        int i = (blk - B_)*256 + tid;     // 0..18431
        int e = i*8;
        const float* src; u16* dst; int off;
        if      (e < 16384) { src = wd;  dst = wdb; off = e; }
        else if (e < 32768) { src = we;  dst = web; off = e - 16384; }
        else if (e < 49152) { src = wp;  dst = wpb; off = e - 32768; }
        else if (e < 98304) { src = wih; dst = wib; off = e - 49152; }
        else                { src = whh; dst = whb; off = e - 98304; }
        float4 a = *(const float4*)(src + off);
        float4 b = *(const float4*)(src + off + 4);
        uint4 r;
        r.x = (u32)f2b(a.x) | ((u32)f2b(a.y) << 16);
        r.y = (u32)f2b(a.z) | ((u32)f2b(a.w) << 16);
        r.z = (u32)f2b(b.x) | ((u32)f2b(b.y) << 16);
        r.w = (u32)f2b(b.z) | ((u32)f2b(b.w) << 16);
        *(uint4*)(dst + off) = r;
        return;
    }

    // ---- prep + scal for batch b ----
    const int b    = blk;
    const int wave = tid >> 6, lane = tid & 63;
    __shared__ float s_hts, s_hi, s_ti, s_is;
    __shared__ float s_part[4];

    const float* hp = emb + (size_t)pair[2*b+0]*D_;
    const float* tp = emb + (size_t)pair[2*b+1]*D_;
    float2 hv = *(const float2*)(hp + 2*lane);
    float2 tv = *(const float2*)(tp + 2*lane);
    float2 uv = *(const float2*)(eu + 2*lane);

    if (wave == 0) {
        float dht = hv.x*tv.x + hv.y*tv.y;
        float dhh = hv.x*hv.x + hv.y*hv.y;
        float dtt = tv.x*tv.x + tv.y*tv.y;
        #pragma unroll
        for (int o = 32; o > 0; o >>= 1) {
            dht += __shfl_xor(dht, o);
            dhh += __shfl_xor(dhh, o);
            dtt += __shfl_xor(dtt, o);
        }
        if (lane == 0) {
            float hn = 1.f / fmaxf(sqrtf(dhh), EPS_);
            float tn = 1.f / fmaxf(sqrtf(dtt), EPS_);
            s_hts = dht*hn*tn;
            s_hi  = hn;
            s_ti  = tn;
        }
    }
    // softmax denominator: 8 relset rows per wave
    float accs = 0.f;
    const float eb = eub[0];
    for (int r = wave*8; r < wave*8 + 8; ++r) {
        const float* ep = emb + (size_t)relset[b*R_+r]*D_;
        float2 ev = *(const float2*)(ep + 2*lane);
        float du = ev.x*uv.x + ev.y*uv.y;
        #pragma unroll
        for (int o = 32; o > 0; o >>= 1) du += __shfl_xor(du, o);
        accs += expf(du + eb);
    }
    if (lane == 0) s_part[wave] = accs;
    __syncthreads();
    if (tid == 0) s_is = 1.f/(s_part[0]+s_part[1]+s_part[2]+s_part[3]);
    __syncthreads();

    const float hi = s_hi, ti = s_ti, ht = s_hts, is = s_is;

    for (int pp = wave; pp < P_; pp += 4) {
        const int bp = b*P_ + pp;
        const float* e1 = emb + (size_t)path[3*bp+0]*D_;
        const float* e2 = emb + (size_t)path[3*bp+1]*D_;
        const float* e3 = emb + (size_t)path[3*bp+2]*D_;
        float2 v1 = *(const float2*)(e1 + 2*lane);
        float2 v2 = *(const float2*)(e2 + 2*lane);
        float2 v3 = *(const float2*)(e3 + 2*lane);
        float d1h = v1.x*hv.x + v1.y*hv.y;
        float d1t = v1.x*tv.x + v1.y*tv.y;
        float n1  = v1.x*v1.x + v1.y*v1.y;
        float d2h = v2.x*hv.x + v2.y*hv.y;
        float d2t = v2.x*tv.x + v2.y*tv.y;
        float n2  = v2.x*v2.x + v2.y*v2.y;
        float u1 = v1.x*uv.x + v1.y*uv.y;
        float u2 = v2.x*uv.x + v2.y*uv.y;
        float u3 = v3.x*uv.x + v3.y*uv.y;
        #pragma unroll
        for (int o = 32; o > 0; o >>= 1) {
            d1h += __shfl_xor(d1h,o); d1t += __shfl_xor(d1t,o); n1 += __shfl_xor(n1,o);
            d2h += __shfl_xor(d2h,o); d2t += __shfl_xor(d2t,o); n2 += __shfl_xor(n2,o);
            u1  += __shfl_xor(u1,o);  u2  += __shfl_xor(u2,o);  u3 += __shfl_xor(u3,o);
        }
        if (lane == 0) {
            float n1i = 1.f / fmaxf(sqrtf(n1), EPS_);
            float n2i = 1.f / fmaxf(sqrtf(n2), EPS_);
            float se1 = 0.5f*(d1h*hi + d1t*ti)*n1i;
            float se2 = 0.5f*(d2h*hi + d2t*ti)*n2i;
            float sr0 = 0.5f*(ht  + se1);
            float sr1 = 0.5f*(se1 + se2);
            float sr2 = 0.5f*(ht  + se2);
            sd[3*bp+0] = (1.f - sr0)*0.5f;
            sd[3*bp+1] = (1.f - sr1)*0.5f;
            sd[3*bp+2] = (1.f - sr2)*0.5f;
            se[3*bp+0] = expf(u1 + eb)*is;
            se[3*bp+1] = expf(u2 + eb)*is;
            se[3*bp+2] = expf(u3 + eb)*is;
        }
    }
}

// ---------------- K2: fused cost pipeline, MFMA bf16 ----------------
// 64 rows/block, waves 1x4; out: relb t-major [3][16384][128] bf16
__global__ __launch_bounds__(256,2) void k_cost(
    const int* __restrict__ path, const float* __restrict__ emb,
    const u16* __restrict__ wdb, const float* __restrict__ bd,
    const u16* __restrict__ web, const float* __restrict__ be,
    const u16* __restrict__ wpb, const float* __restrict__ bp,
    const float* __restrict__ sdg, const float* __restrict__ seg,
    u16* __restrict__ relb)
{
    __shared__ u16   Xs[64*128];          // 16 KB, swizzled bf16 tile
    __shared__ float sdS[64], seS[64];
    __shared__ int   pS[64];
    const int tid  = threadIdx.x;
    const int base = blockIdx.x * 64;

    if (tid < 64) {
        pS[tid]  = path[base + tid];
        sdS[tid] = sdg[base + tid];
        seS[tid] = seg[base + tid];
    }
    __syncthreads();

    #pragma unroll
    for (int i = 0; i < 4; ++i) {
        int gid = i*256 + tid;            // 1024 granules of 8 bf16
        int r = gid >> 4, g = gid & 15;
        const float* sp = emb + (size_t)pS[r]*128 + g*8;
        float4 f0 = *(const float4*)sp;
        float4 f1 = *(const float4*)(sp + 4);
        bf16x8 v = pack8(f0.x,f0.y,f0.z,f0.w, f1.x,f1.y,f1.z,f1.w);
        *(uint4*)(&Xs[r*128 + ((g ^ (r & 7)) << 3)]) = __builtin_bit_cast(uint4, v);
    }
    __syncthreads();

    const int wave = tid >> 6, lane = tid & 63;
    const int lrow = lane & 15, lk8 = lane >> 4;
    const int wn = wave;

    f32x4 accD[4][2], accE[4][2];
    #pragma unroll
    for (int m = 0; m < 4; ++m)
        #pragma unroll
        for (int n = 0; n < 2; ++n) { accD[m][n] = (f32x4){0,0,0,0}; accE[m][n] = (f32x4){0,0,0,0}; }

    #pragma unroll
    for (int ks = 0; ks < 4; ++ks) {
        const int gk = ks*4 + lk8;
        bf16x8 a[4];
        #pragma unroll
        for (int mt = 0; mt < 4; ++mt) a[mt] = ldA(Xs, mt*16 + lrow, gk);
        #pragma unroll
        for (int nt = 0; nt < 2; ++nt) {
            const int n = wn*32 + nt*16 + lrow;
            bf16x8 bD = ldg8(wdb + n*128 + gk*8);
            bf16x8 bE = ldg8(web + n*128 + gk*8);
            #pragma unroll
            for (int mt = 0; mt < 4; ++mt) {
                accD[mt][nt] = __builtin_amdgcn_mfma_f32_16x16x32_bf16(a[mt], bD, accD[mt][nt], 0,0,0);
                accE[mt][nt] = __builtin_amdgcn_mfma_f32_16x16x32_bf16(a[mt], bE, accE[mt][nt], 0,0,0);
            }
        }
    }
    __syncthreads();

    #pragma unroll
    for (int nt = 0; nt < 2; ++nt) {
        const int col = wn*32 + nt*16 + lrow;
        const float bde = bd[col] + be[col];
        #pragma unroll
        for (int mt = 0; mt < 4; ++mt) {
            #pragma unroll
            for (int rr = 0; rr < 4; ++rr) {
                const int row = mt*16 + lk8*4 + rr;
                const int sl  = swz_slot(row, col);
                float relv = b2f(Xs[sl]);
                float c = sdS[row]*accD[mt][nt][rr] + seS[row]*accE[mt][nt][rr] + bde;
                Xs[sl] = f2b(relv - 1e-3f*fmaxf(c, 0.f));
            }
        }
    }
    __syncthreads();

    f32x4 accP[4][2];
    #pragma unroll
    for (int m = 0; m < 4; ++m)
        #pragma unroll
        for (int n = 0; n < 2; ++n) accP[m][n] = (f32x4){0,0,0,0};
    #pragma unroll
    for (int ks = 0; ks < 4; ++ks) {
        const int gk = ks*4 + lk8;
        bf16x8 a[4];
        #pragma unroll
        for (int mt = 0; mt < 4; ++mt) a[mt] = ldA(Xs, mt*16 + lrow, gk);
        #pragma unroll
        for (int nt = 0; nt < 2; ++nt) {
            const int n = wn*32 + nt*16 + lrow;
            bf16x8 bP = ldg8(wpb + n*128 + gk*8);
            #pragma unroll
            for (int mt = 0; mt < 4; ++mt)
                accP[mt][nt] = __builtin_amdgcn_mfma_f32_16x16x32_bf16(a[mt], bP, accP[mt][nt], 0,0,0);
        }
    }

    #pragma unroll
    for (int nt = 0; nt < 2; ++nt) {
        const int col = wn*32 + nt*16 + lrow;
        const float bpv = bp[col];
        #pragma unroll
        for (int mt = 0; mt < 4; ++mt) {
            #pragma unroll
            for (int rr = 0; rr < 4; ++rr) {
                const int row  = mt*16 + lk8*4 + rr;
                const int grow = base + row;
                const int tt   = grow - (grow/3)*3;
                const int bprow= grow/3;
                relb[((size_t)tt*NBP + bprow)*128 + col] = f2b(accP[mt][nt][rr] + bpv);
            }
        }
    }
}

// ---------------- K3: full GRU, all 3 timesteps in one launch ----------------
// 32 rows/block, 512 blocks; h in LDS (bf16, swizzled) + fp32 regs for carry
__global__ __launch_bounds__(256,2) void k_gru3(
    const u16* __restrict__ relb,    // [3][16384][128] bf16, t-major
    const u16* __restrict__ wib, const u16* __restrict__ whb,
    const float* __restrict__ bih, const float* __restrict__ bhh,
    float* __restrict__ out)
{
    __shared__ u16 Hs[32*128];        // 8 KB swizzled bf16
    const int tid  = threadIdx.x;
    const int bp0  = blockIdx.x * 32;
    const int wave = tid >> 6, lane = tid & 63;
    const int lrow = lane & 15, lk8 = lane >> 4;
    const int wn = wave;

    // per-lane biases for its two columns
    float brv[2], bzv[2], biN[2], bhN[2];
    #pragma unroll
    for (int nt = 0; nt < 2; ++nt) {
        const int col = wn*32 + nt*16 + lrow;
        brv[nt] = bih[col]       + bhh[col];
        bzv[nt] = bih[128 + col] + bhh[128 + col];
        biN[nt] = bih[256 + col];
        bhN[nt] = bhh[256 + col];
    }

    float hreg[2][2][4];              // fp32 carry of this lane's h elements
    #pragma unroll
    for (int m = 0; m < 2; ++m)
        #pragma unroll
        for (int n = 0; n < 2; ++n)
            #pragma unroll
            for (int r = 0; r < 4; ++r) hreg[m][n][r] = 0.f;

    for (int t = 0; t < 3; ++t) {
        const u16* xsl = relb + (size_t)t*NBP*128;

        f32x4 accR[2][2], accZ[2][2], accI[2][2], accH[2][2];
        #pragma unroll
        for (int m = 0; m < 2; ++m)
            #pragma unroll
            for (int n = 0; n < 2; ++n) {
                accR[m][n] = (f32x4){0,0,0,0}; accZ[m][n] = (f32x4){0,0,0,0};
                accI[m][n] = (f32x4){0,0,0,0}; accH[m][n] = (f32x4){0,0,0,0};
            }

        #pragma unroll
        for (int ks = 0; ks < 4; ++ks) {
            const int gk = ks*4 + lk8;
            bf16x8 ax[2];
            #pragma unroll
            for (int mt = 0; mt < 2; ++mt)
                ax[mt] = ldg8(xsl + (size_t)(bp0 + mt*16 + lrow)*128 + gk*8);
            #pragma unroll
            for (int nt = 0; nt < 2; ++nt) {
                const int n = wn*32 + nt*16 + lrow;
                bf16x8 bR = ldg8(wib + n*128 + gk*8);
                bf16x8 bZ = ldg8(wib + 16384 + n*128 + gk*8);
                bf16x8 bI = ldg8(wib + 2*16384 + n*128 + gk*8);
                #pragma unroll
                for (int mt = 0; mt < 2; ++mt) {
                    accR[mt][nt] = __builtin_amdgcn_mfma_f32_16x16x32_bf16(ax[mt], bR, accR[mt][nt], 0,0,0);
                    accZ[mt][nt] = __builtin_amdgcn_mfma_f32_16x16x32_bf16(ax[mt], bZ, accZ[mt][nt], 0,0,0);
                    accI[mt][nt] = __builtin_amdgcn_mfma_f32_16x16x32_bf16(ax[mt], bI, accI[mt][nt], 0,0,0);
                }
            }
            if (t > 0) {
                bf16x8 ah[2];
                #pragma unroll
                for (int mt = 0; mt < 2; ++mt)
                    ah[mt] = ldA(Hs, mt*16 + lrow, gk);
                #pragma unroll
                for (int nt = 0; nt < 2; ++nt) {
                    const int n = wn*32 + nt*16 + lrow;
                    bf16x8 cR = ldg8(whb + n*128 + gk*8);
                    bf16x8 cZ = ldg8(whb + 16384 + n*128 + gk*8);
                    bf16x8 cH = ldg8(whb + 2*16384 + n*128 + gk*8);
                    #pragma unroll
                    for (int mt = 0; mt < 2; ++mt) {
                        accR[mt][nt] = __builtin_amdgcn_mfma_f32_16x16x32_bf16(ah[mt], cR, accR[mt][nt], 0,0,0);
                        accZ[mt][nt] = __builtin_amdgcn_mfma_f32_16x16x32_bf16(ah[mt], cZ, accZ[mt][nt], 0,0,0);
                        accH[mt][nt] = __builtin_amdgcn_mfma_f32_16x16x32_bf16(ah[mt], cH, accH[mt][nt], 0,0,0);
                    }
                }
            }
        }
        __syncthreads();   // all Hs reads for this step complete

        // combine + write back
        #pragma unroll
        for (int nt = 0; nt < 2; ++nt) {
            const int col = wn*32 + nt*16 + lrow;
            #pragma unroll
            for (int mt = 0; mt < 2; ++mt) {
                #pragma unroll
                for (int rr = 0; rr < 4; ++rr) {
                    const int row = mt*16 + lk8*4 + rr;
                    float rv = sigm(accR[mt][nt][rr] + brv[nt]);
                    float zv = sigm(accZ[mt][nt][rr] + bzv[nt]);
                    float hn = accH[mt][nt][rr] + bhN[nt];
                    float nn = tanhf(accI[mt][nt][rr] + biN[nt] + rv*hn);
                    float hp = (t == 0) ? 0.f : hreg[mt][nt][rr];
                    float hv2 = (1.f - zv)*nn + zv*hp;
                    hreg[mt][nt][rr] = hv2;
                    if (t < 2) Hs[swz_slot(row, col)] = f2b(hv2);
                    else       out[(size_t)(bp0 + row)*128 + col] = hv2;
                }
            }
        }
        if (t < 2) __syncthreads();   // Hs writes visible before next step's reads
    }
}

extern "C" void kernel_launch(void* const* d_in, const int* in_sizes, int n_in,
                              void* d_out, int out_size, void* d_ws, size_t ws_size,
                              hipStream_t stream)
{
    const int*   path   = (const int*)d_in[0];
    const int*   pair   = (const int*)d_in[1];
    const int*   relset = (const int*)d_in[2];
    const float* emb    = (const float*)d_in[3];
    const float* wd     = (const float*)d_in[4];
    const float* bd     = (const float*)d_in[5];
    const float* we     = (const float*)d_in[6];
    const float* be     = (const float*)d_in[7];
    const float* wp     = (const float*)d_in[8];
    const float* bp     = (const float*)d_in[9];
    const float* eu     = (const float*)d_in[10];
    const float* eub    = (const float*)d_in[11];
    const float* wih    = (const float*)d_in[12];
    const float* whh    = (const float*)d_in[13];
    const float* bih    = (const float*)d_in[14];
    const float* bhh    = (const float*)d_in[15];
    float* out = (float*)d_out;
    float* ws  = (float*)d_ws;

    // workspace (float offsets), total ~12.7 MB
    float* sdg  = ws;                      // 49152
    float* seg  = ws + NROW;               // 49152 -> ends 98304
    u16*   relb = (u16*)(ws + 98304);      // 3*16384*128 bf16 -> ends 3244032
    u16*   wdb  = (u16*)(ws + 3244032);    // -> 3252224
    u16*   web  = (u16*)(ws + 3252224);    // -> 3260416
    u16*   wpb  = (u16*)(ws + 3260416);    // -> 3268608
    u16*   wib  = (u16*)(ws + 3268608);    // -> 3293184
    u16*   whb  = (u16*)(ws + 3293184);    // -> 3317760 (12.7 MB)

    k_fuse0<<<B_ + 72, 256, 0, stream>>>(pair, relset, path, emb, eu, eub,
                                         wd, we, wp, wih, whh,
                                         wdb, web, wpb, wib, whb, sdg, seg);
    k_cost <<<NROW/64, 256, 0, stream>>>(path, emb, wdb, bd, web, be, wpb, bp,
                                         sdg, seg, relb);
    k_gru3 <<<NBP/32,  256, 0, stream>>>(relb, wib, whb, bih, bhh, out);
}

// Round 6
// 80.023 us; speedup vs baseline: 5.1237x; 1.1711x over previous
//
#include <hip/hip_runtime.h>
#include <cmath>

#define D_ 128
#define B_ 256
#define P_ 64
#define R_ 32
#define NROW (B_*P_*3)   /* 49152 */
#define NBP  (B_*P_)     /* 16384 */
#define EPS_ 1e-8f

typedef unsigned short u16;
typedef unsigned int   u32;
using bf16x8 = __attribute__((ext_vector_type(8))) __bf16;
using f32x4  = __attribute__((ext_vector_type(4))) float;

__device__ __forceinline__ float sigm(float x){ return 1.0f/(1.0f + expf(-x)); }
// fast variants for GRU combine (error ~1e-6, far below bf16 rounding)
__device__ __forceinline__ float sigm_f(float x){ return 1.0f/(1.0f + __expf(-x)); }
__device__ __forceinline__ float tanh_f(float x){
    float e = __expf(2.0f*x);
    return 1.0f - 2.0f/(e + 1.0f);
}

__device__ __forceinline__ u16 f2b(float f){         // fp32 -> bf16 RNE
    u32 u = __builtin_bit_cast(u32, f);
    u += 0x7fffu + ((u >> 16) & 1u);
    return (u16)(u >> 16);
}
__device__ __forceinline__ float b2f(u16 s){
    return __builtin_bit_cast(float, ((u32)s) << 16);
}
__device__ __forceinline__ bf16x8 pack8(float a0,float a1,float a2,float a3,
                                        float a4,float a5,float a6,float a7){
    uint4 r;
    r.x = (u32)f2b(a0) | ((u32)f2b(a1) << 16);
    r.y = (u32)f2b(a2) | ((u32)f2b(a3) << 16);
    r.z = (u32)f2b(a4) | ((u32)f2b(a5) << 16);
    r.w = (u32)f2b(a6) | ((u32)f2b(a7) << 16);
    return __builtin_bit_cast(bf16x8, r);
}
__device__ __forceinline__ bf16x8 ldg8(const u16* p){
    return __builtin_bit_cast(bf16x8, *(const uint4*)p);
}
// swizzled LDS bf16 tile: slot(row, granule g) at row*128 + ((g^(row&7))<<3)
__device__ __forceinline__ bf16x8 ldA(const u16* Xs, int row, int gk){
    return __builtin_bit_cast(bf16x8,
        *(const uint4*)(&Xs[row*128 + ((gk ^ (row & 7)) << 3)]));
}
__device__ __forceinline__ int swz_slot(int row, int col){
    return row*128 + (((col >> 3) ^ (row & 7)) << 3) + (col & 7);
}

// ---------------- K1: fused prep + scal + weight-convert ----------------
__global__ __launch_bounds__(256) void k_fuse0(
    const int* __restrict__ pair, const int* __restrict__ relset,
    const int* __restrict__ path,
    const float* __restrict__ emb, const float* __restrict__ eu,
    const float* __restrict__ eub,
    const float* __restrict__ wd, const float* __restrict__ we,
    const float* __restrict__ wp, const float* __restrict__ wih,
    const float* __restrict__ whh,
    u16* __restrict__ wdb, u16* __restrict__ web, u16* __restrict__ wpb,
    u16* __restrict__ wib, u16* __restrict__ whb,
    float* __restrict__ sd, float* __restrict__ se)
{
    const int blk = blockIdx.x;
    const int tid = threadIdx.x;

    if (blk >= B_) {           // ---- weight convert region ----
        int i = (blk - B_)*256 + tid;     // 0..18431
        int e = i*8;
        const float* src; u16* dst; int off;
        if      (e < 16384) { src = wd;  dst = wdb; off = e; }
        else if (e < 32768) { src = we;  dst = web; off = e - 16384; }
        else if (e < 49152) { src = wp;  dst = wpb; off = e - 32768; }
        else if (e < 98304) { src = wih; dst = wib; off = e - 49152; }
        else                { src = whh; dst = whb; off = e - 98304; }
        float4 a = *(const float4*)(src + off);
        float4 b = *(const float4*)(src + off + 4);
        uint4 r;
        r.x = (u32)f2b(a.x) | ((u32)f2b(a.y) << 16);
        r.y = (u32)f2b(a.z) | ((u32)f2b(a.w) << 16);
        r.z = (u32)f2b(b.x) | ((u32)f2b(b.y) << 16);
        r.w = (u32)f2b(b.z) | ((u32)f2b(b.w) << 16);
        *(uint4*)(dst + off) = r;
        return;
    }

    // ---- prep + scal for batch b ----
    const int b    = blk;
    const int wave = tid >> 6, lane = tid & 63;
    __shared__ float s_hts, s_hi, s_ti, s_is;
    __shared__ float s_part[4];

    const float* hp = emb + (size_t)pair[2*b+0]*D_;
    const float* tp = emb + (size_t)pair[2*b+1]*D_;
    float2 hv = *(const float2*)(hp + 2*lane);
    float2 tv = *(const float2*)(tp + 2*lane);
    float2 uv = *(const float2*)(eu + 2*lane);

    if (wave == 0) {
        float dht = hv.x*tv.x + hv.y*tv.y;
        float dhh = hv.x*hv.x + hv.y*hv.y;
        float dtt = tv.x*tv.x + tv.y*tv.y;
        #pragma unroll
        for (int o = 32; o > 0; o >>= 1) {
            dht += __shfl_xor(dht, o);
            dhh += __shfl_xor(dhh, o);
            dtt += __shfl_xor(dtt, o);
        }
        if (lane == 0) {
            float hn = 1.f / fmaxf(sqrtf(dhh), EPS_);
            float tn = 1.f / fmaxf(sqrtf(dtt), EPS_);
            s_hts = dht*hn*tn;
            s_hi  = hn;
            s_ti  = tn;
        }
    }
    float accs = 0.f;
    const float eb = eub[0];
    for (int r = wave*8; r < wave*8 + 8; ++r) {
        const float* ep = emb + (size_t)relset[b*R_+r]*D_;
        float2 ev = *(const float2*)(ep + 2*lane);
        float du = ev.x*uv.x + ev.y*uv.y;
        #pragma unroll
        for (int o = 32; o > 0; o >>= 1) du += __shfl_xor(du, o);
        accs += expf(du + eb);
    }
    if (lane == 0) s_part[wave] = accs;
    __syncthreads();
    if (tid == 0) s_is = 1.f/(s_part[0]+s_part[1]+s_part[2]+s_part[3]);
    __syncthreads();

    const float hi = s_hi, ti = s_ti, ht = s_hts, is = s_is;

    for (int pp = wave; pp < P_; pp += 4) {
        const int bp = b*P_ + pp;
        const float* e1 = emb + (size_t)path[3*bp+0]*D_;
        const float* e2 = emb + (size_t)path[3*bp+1]*D_;
        const float* e3 = emb + (size_t)path[3*bp+2]*D_;
        float2 v1 = *(const float2*)(e1 + 2*lane);
        float2 v2 = *(const float2*)(e2 + 2*lane);
        float2 v3 = *(const float2*)(e3 + 2*lane);
        float d1h = v1.x*hv.x + v1.y*hv.y;
        float d1t = v1.x*tv.x + v1.y*tv.y;
        float n1  = v1.x*v1.x + v1.y*v1.y;
        float d2h = v2.x*hv.x + v2.y*hv.y;
        float d2t = v2.x*tv.x + v2.y*tv.y;
        float n2  = v2.x*v2.x + v2.y*v2.y;
        float u1 = v1.x*uv.x + v1.y*uv.y;
        float u2 = v2.x*uv.x + v2.y*uv.y;
        float u3 = v3.x*uv.x + v3.y*uv.y;
        #pragma unroll
        for (int o = 32; o > 0; o >>= 1) {
            d1h += __shfl_xor(d1h,o); d1t += __shfl_xor(d1t,o); n1 += __shfl_xor(n1,o);
            d2h += __shfl_xor(d2h,o); d2t += __shfl_xor(d2t,o); n2 += __shfl_xor(n2,o);
            u1  += __shfl_xor(u1,o);  u2  += __shfl_xor(u2,o);  u3 += __shfl_xor(u3,o);
        }
        if (lane == 0) {
            float n1i = 1.f / fmaxf(sqrtf(n1), EPS_);
            float n2i = 1.f / fmaxf(sqrtf(n2), EPS_);
            float se1 = 0.5f*(d1h*hi + d1t*ti)*n1i;
            float se2 = 0.5f*(d2h*hi + d2t*ti)*n2i;
            float sr0 = 0.5f*(ht  + se1);
            float sr1 = 0.5f*(se1 + se2);
            float sr2 = 0.5f*(ht  + se2);
            sd[3*bp+0] = (1.f - sr0)*0.5f;
            sd[3*bp+1] = (1.f - sr1)*0.5f;
            sd[3*bp+2] = (1.f - sr2)*0.5f;
            se[3*bp+0] = expf(u1 + eb)*is;
            se[3*bp+1] = expf(u2 + eb)*is;
            se[3*bp+2] = expf(u3 + eb)*is;
        }
    }
}

// ---------------- K2: fused cost pipeline, MFMA bf16 ----------------
__global__ __launch_bounds__(256,2) void k_cost(
    const int* __restrict__ path, const float* __restrict__ emb,
    const u16* __restrict__ wdb, const float* __restrict__ bd,
    const u16* __restrict__ web, const float* __restrict__ be,
    const u16* __restrict__ wpb, const float* __restrict__ bp,
    const float* __restrict__ sdg, const float* __restrict__ seg,
    u16* __restrict__ relb)
{
    __shared__ u16   Xs[64*128];
    __shared__ float sdS[64], seS[64];
    __shared__ int   pS[64];
    const int tid  = threadIdx.x;
    const int base = blockIdx.x * 64;

    if (tid < 64) {
        pS[tid]  = path[base + tid];
        sdS[tid] = sdg[base + tid];
        seS[tid] = seg[base + tid];
    }
    __syncthreads();

    #pragma unroll
    for (int i = 0; i < 4; ++i) {
        int gid = i*256 + tid;
        int r = gid >> 4, g = gid & 15;
        const float* sp = emb + (size_t)pS[r]*128 + g*8;
        float4 f0 = *(const float4*)sp;
        float4 f1 = *(const float4*)(sp + 4);
        bf16x8 v = pack8(f0.x,f0.y,f0.z,f0.w, f1.x,f1.y,f1.z,f1.w);
        *(uint4*)(&Xs[r*128 + ((g ^ (r & 7)) << 3)]) = __builtin_bit_cast(uint4, v);
    }
    __syncthreads();

    const int wave = tid >> 6, lane = tid & 63;
    const int lrow = lane & 15, lk8 = lane >> 4;
    const int wn = wave;

    f32x4 accD[4][2], accE[4][2];
    #pragma unroll
    for (int m = 0; m < 4; ++m)
        #pragma unroll
        for (int n = 0; n < 2; ++n) { accD[m][n] = (f32x4){0,0,0,0}; accE[m][n] = (f32x4){0,0,0,0}; }

    #pragma unroll
    for (int ks = 0; ks < 4; ++ks) {
        const int gk = ks*4 + lk8;
        bf16x8 a[4];
        #pragma unroll
        for (int mt = 0; mt < 4; ++mt) a[mt] = ldA(Xs, mt*16 + lrow, gk);
        #pragma unroll
        for (int nt = 0; nt < 2; ++nt) {
            const int n = wn*32 + nt*16 + lrow;
            bf16x8 bD = ldg8(wdb + n*128 + gk*8);
            bf16x8 bE = ldg8(web + n*128 + gk*8);
            #pragma unroll
            for (int mt = 0; mt < 4; ++mt) {
                accD[mt][nt] = __builtin_amdgcn_mfma_f32_16x16x32_bf16(a[mt], bD, accD[mt][nt], 0,0,0);
                accE[mt][nt] = __builtin_amdgcn_mfma_f32_16x16x32_bf16(a[mt], bE, accE[mt][nt], 0,0,0);
            }
        }
    }
    __syncthreads();

    #pragma unroll
    for (int nt = 0; nt < 2; ++nt) {
        const int col = wn*32 + nt*16 + lrow;
        const float bde = bd[col] + be[col];
        #pragma unroll
        for (int mt = 0; mt < 4; ++mt) {
            #pragma unroll
            for (int rr = 0; rr < 4; ++rr) {
                const int row = mt*16 + lk8*4 + rr;
                const int sl  = swz_slot(row, col);
                float relv = b2f(Xs[sl]);
                float c = sdS[row]*accD[mt][nt][rr] + seS[row]*accE[mt][nt][rr] + bde;
                Xs[sl] = f2b(relv - 1e-3f*fmaxf(c, 0.f));
            }
        }
    }
    __syncthreads();

    f32x4 accP[4][2];
    #pragma unroll
    for (int m = 0; m < 4; ++m)
        #pragma unroll
        for (int n = 0; n < 2; ++n) accP[m][n] = (f32x4){0,0,0,0};
    #pragma unroll
    for (int ks = 0; ks < 4; ++ks) {
        const int gk = ks*4 + lk8;
        bf16x8 a[4];
        #pragma unroll
        for (int mt = 0; mt < 4; ++mt) a[mt] = ldA(Xs, mt*16 + lrow, gk);
        #pragma unroll
        for (int nt = 0; nt < 2; ++nt) {
            const int n = wn*32 + nt*16 + lrow;
            bf16x8 bP = ldg8(wpb + n*128 + gk*8);
            #pragma unroll
            for (int mt = 0; mt < 4; ++mt)
                accP[mt][nt] = __builtin_amdgcn_mfma_f32_16x16x32_bf16(a[mt], bP, accP[mt][nt], 0,0,0);
        }
    }

    #pragma unroll
    for (int nt = 0; nt < 2; ++nt) {
        const int col = wn*32 + nt*16 + lrow;
        const float bpv = bp[col];
        #pragma unroll
        for (int mt = 0; mt < 4; ++mt) {
            #pragma unroll
            for (int rr = 0; rr < 4; ++rr) {
                const int row  = mt*16 + lk8*4 + rr;
                const int grow = base + row;
                const int tt   = grow - (grow/3)*3;
                const int bprow= grow/3;
                relb[((size_t)tt*NBP + bprow)*128 + col] = f2b(accP[mt][nt][rr] + bpv);
            }
        }
    }
}

// ---------------- K3: full GRU, register-resident weights ----------------
// 512 threads (8 waves), 64 rows/block, grid 256 = 1 block/CU.
// Each wave owns a 16-col strip; its B-fragments for all 6 weight matrices
// live in registers (24 x bf16x8 = 96 VGPR), loaded ONCE.
__global__ __launch_bounds__(512,2) void k_gru3(
    const u16* __restrict__ relb,    // [3][16384][128] bf16, t-major
    const u16* __restrict__ wib, const u16* __restrict__ whb,
    const float* __restrict__ bih, const float* __restrict__ bhh,
    float* __restrict__ out)
{
    __shared__ u16 Hs[64*128];        // 16 KB swizzled bf16
    const int tid  = threadIdx.x;
    const int bp0  = blockIdx.x * 64;
    const int wave = tid >> 6, lane = tid & 63;
    const int lrow = lane & 15, lk8 = lane >> 4;
    const int col  = wave*16 + lrow;  // this lane's output column

    // ---- preload all weight fragments into registers ----
    bf16x8 wR[4], wZ[4], wI[4], vR[4], vZ[4], vH[4];
    #pragma unroll
    for (int ks = 0; ks < 4; ++ks) {
        const int gk = ks*4 + lk8;
        wR[ks] = ldg8(wib +             col*128 + gk*8);
        wZ[ks] = ldg8(wib + 16384     + col*128 + gk*8);
        wI[ks] = ldg8(wib + 2*16384   + col*128 + gk*8);
        vR[ks] = ldg8(whb +             col*128 + gk*8);
        vZ[ks] = ldg8(whb + 16384     + col*128 + gk*8);
        vH[ks] = ldg8(whb + 2*16384   + col*128 + gk*8);
    }
    const float brv = bih[col]       + bhh[col];
    const float bzv = bih[128 + col] + bhh[128 + col];
    const float biN = bih[256 + col];
    const float bhN = bhh[256 + col];

    float hreg[4][4];                 // fp32 carry: [mt][rr]
    #pragma unroll
    for (int m = 0; m < 4; ++m)
        #pragma unroll
        for (int r = 0; r < 4; ++r) hreg[m][r] = 0.f;

    for (int t = 0; t < 3; ++t) {
        const u16* xsl = relb + (size_t)t*NBP*128;

        f32x4 aR[4], aZ[4], aI[4], aH[4];
        #pragma unroll
        for (int m = 0; m < 4; ++m) {
            aR[m] = (f32x4){0,0,0,0}; aZ[m] = (f32x4){0,0,0,0};
            aI[m] = (f32x4){0,0,0,0}; aH[m] = (f32x4){0,0,0,0};
        }

        #pragma unroll
        for (int ks = 0; ks < 4; ++ks) {
            const int gk = ks*4 + lk8;
            bf16x8 ax[4];
            #pragma unroll
            for (int mt = 0; mt < 4; ++mt)
                ax[mt] = ldg8(xsl + (size_t)(bp0 + mt*16 + lrow)*128 + gk*8);
            #pragma unroll
            for (int mt = 0; mt < 4; ++mt) {
                aR[mt] = __builtin_amdgcn_mfma_f32_16x16x32_bf16(ax[mt], wR[ks], aR[mt], 0,0,0);
                aZ[mt] = __builtin_amdgcn_mfma_f32_16x16x32_bf16(ax[mt], wZ[ks], aZ[mt], 0,0,0);
                aI[mt] = __builtin_amdgcn_mfma_f32_16x16x32_bf16(ax[mt], wI[ks], aI[mt], 0,0,0);
            }
            if (t > 0) {
                bf16x8 ah[4];
                #pragma unroll
                for (int mt = 0; mt < 4; ++mt)
                    ah[mt] = ldA(Hs, mt*16 + lrow, gk);
                #pragma unroll
                for (int mt = 0; mt < 4; ++mt) {
                    aR[mt] = __builtin_amdgcn_mfma_f32_16x16x32_bf16(ah[mt], vR[ks], aR[mt], 0,0,0);
                    aZ[mt] = __builtin_amdgcn_mfma_f32_16x16x32_bf16(ah[mt], vZ[ks], aZ[mt], 0,0,0);
                    aH[mt] = __builtin_amdgcn_mfma_f32_16x16x32_bf16(ah[mt], vH[ks], aH[mt], 0,0,0);
                }
            }
        }
        __syncthreads();   // all Hs reads of this step complete

        // combine + write back
        #pragma unroll
        for (int mt = 0; mt < 4; ++mt) {
            #pragma unroll
            for (int rr = 0; rr < 4; ++rr) {
                const int row = mt*16 + lk8*4 + rr;
                float rv = sigm_f(aR[mt][rr] + brv);
                float zv = sigm_f(aZ[mt][rr] + bzv);
                float hn = aH[mt][rr] + bhN;
                float nn = tanh_f(aI[mt][rr] + biN + rv*hn);
                float hp = (t == 0) ? 0.f : hreg[mt][rr];
                float h2 = (1.f - zv)*nn + zv*hp;
                hreg[mt][rr] = h2;
                if (t < 2) Hs[swz_slot(row, col)] = f2b(h2);
                else       out[(size_t)(bp0 + row)*128 + col] = h2;
            }
        }
        if (t < 2) __syncthreads();   // Hs writes visible before next step
    }
}

extern "C" void kernel_launch(void* const* d_in, const int* in_sizes, int n_in,
                              void* d_out, int out_size, void* d_ws, size_t ws_size,
                              hipStream_t stream)
{
    const int*   path   = (const int*)d_in[0];
    const int*   pair   = (const int*)d_in[1];
    const int*   relset = (const int*)d_in[2];
    const float* emb    = (const float*)d_in[3];
    const float* wd     = (const float*)d_in[4];
    const float* bd     = (const float*)d_in[5];
    const float* we     = (const float*)d_in[6];
    const float* be     = (const float*)d_in[7];
    const float* wp     = (const float*)d_in[8];
    const float* bp     = (const float*)d_in[9];
    const float* eu     = (const float*)d_in[10];
    const float* eub    = (const float*)d_in[11];
    const float* wih    = (const float*)d_in[12];
    const float* whh    = (const float*)d_in[13];
    const float* bih    = (const float*)d_in[14];
    const float* bhh    = (const float*)d_in[15];
    float* out = (float*)d_out;
    float* ws  = (float*)d_ws;

    // workspace (float offsets), total ~12.7 MB
    float* sdg  = ws;                      // 49152
    float* seg  = ws + NROW;               // 49152 -> ends 98304
    u16*   relb = (u16*)(ws + 98304);      // 3*16384*128 bf16 -> ends 3244032
    u16*   wdb  = (u16*)(ws + 3244032);    // -> 3252224
    u16*   web  = (u16*)(ws + 3252224);    // -> 3260416
    u16*   wpb  = (u16*)(ws + 3260416);    // -> 3268608
    u16*   wib  = (u16*)(ws + 3268608);    // -> 3293184
    u16*   whb  = (u16*)(ws + 3293184);    // -> 3317760 (12.7 MB)

    k_fuse0<<<B_ + 72, 256, 0, stream>>>(pair, relset, path, emb, eu, eub,
                                         wd, we, wp, wih, whh,
                                         wdb, web, wpb, wib, whb, sdg, seg);
    k_cost <<<NROW/64, 256, 0, stream>>>(path, emb, wdb, bd, web, be, wpb, bp,
                                         sdg, seg, relb);
    k_gru3 <<<NBP/64,  512, 0, stream>>>(relb, wib, whb, bih, bhh, out);
}

// Round 7
// 59.754 us; speedup vs baseline: 6.8617x; 1.3392x over previous
//
#include <hip/hip_runtime.h>
#include <cmath>

#define D_ 128
#define B_ 256
#define P_ 64
#define R_ 32
#define NROW (B_*P_*3)   /* 49152 */
#define NBP  (B_*P_)     /* 16384 */
#define EPS_ 1e-8f

typedef unsigned short u16;
typedef unsigned int   u32;
using bf16x8 = __attribute__((ext_vector_type(8))) __bf16;
using f32x4  = __attribute__((ext_vector_type(4))) float;

__device__ __forceinline__ float sigm_f(float x){ return 1.0f/(1.0f + __expf(-x)); }
__device__ __forceinline__ float tanh_f(float x){
    float e = __expf(2.0f*x);
    return 1.0f - 2.0f/(e + 1.0f);
}

__device__ __forceinline__ u16 f2b(float f){         // fp32 -> bf16 RNE
    u32 u = __builtin_bit_cast(u32, f);
    u += 0x7fffu + ((u >> 16) & 1u);
    return (u16)(u >> 16);
}
__device__ __forceinline__ float b2f(u16 s){
    return __builtin_bit_cast(float, ((u32)s) << 16);
}
__device__ __forceinline__ bf16x8 pack8(float a0,float a1,float a2,float a3,
                                        float a4,float a5,float a6,float a7){
    uint4 r;
    r.x = (u32)f2b(a0) | ((u32)f2b(a1) << 16);
    r.y = (u32)f2b(a2) | ((u32)f2b(a3) << 16);
    r.z = (u32)f2b(a4) | ((u32)f2b(a5) << 16);
    r.w = (u32)f2b(a6) | ((u32)f2b(a7) << 16);
    return __builtin_bit_cast(bf16x8, r);
}
__device__ __forceinline__ bf16x8 ldg8(const u16* p){
    return __builtin_bit_cast(bf16x8, *(const uint4*)p);
}
// swizzled LDS bf16 tile: slot(row, granule g) at row*128 + ((g^(row&7))<<3)
__device__ __forceinline__ bf16x8 ldA(const u16* Xs, int row, int gk){
    return __builtin_bit_cast(bf16x8,
        *(const uint4*)(&Xs[row*128 + ((gk ^ (row & 7)) << 3)]));
}
__device__ __forceinline__ int swz_slot(int row, int col){
    return row*128 + (((col >> 3) ^ (row & 7)) << 3) + (col & 7);
}

// ---------------- K1: fused prep + scal + weight-convert (1024 thr) ----------------
__global__ __launch_bounds__(1024) void k_fuse0(
    const int* __restrict__ pair, const int* __restrict__ relset,
    const int* __restrict__ path,
    const float* __restrict__ emb, const float* __restrict__ eu,
    const float* __restrict__ eub,
    const float* __restrict__ wd, const float* __restrict__ we,
    const float* __restrict__ wp, const float* __restrict__ wih,
    const float* __restrict__ whh,
    u16* __restrict__ wdb, u16* __restrict__ web, u16* __restrict__ wpb,
    u16* __restrict__ wib, u16* __restrict__ whb,
    float* __restrict__ sd, float* __restrict__ se)
{
    const int blk = blockIdx.x;
    const int tid = threadIdx.x;

    if (blk >= B_) {           // ---- weight convert region ----
        int i = (blk - B_)*1024 + tid;    // 0..18431
        int e = i*8;
        const float* src; u16* dst; int off;
        if      (e < 16384) { src = wd;  dst = wdb; off = e; }
        else if (e < 32768) { src = we;  dst = web; off = e - 16384; }
        else if (e < 49152) { src = wp;  dst = wpb; off = e - 32768; }
        else if (e < 98304) { src = wih; dst = wib; off = e - 49152; }
        else                { src = whh; dst = whb; off = e - 98304; }
        float4 a = *(const float4*)(src + off);
        float4 b = *(const float4*)(src + off + 4);
        uint4 r;
        r.x = (u32)f2b(a.x) | ((u32)f2b(a.y) << 16);
        r.y = (u32)f2b(a.z) | ((u32)f2b(a.w) << 16);
        r.z = (u32)f2b(b.x) | ((u32)f2b(b.y) << 16);
        r.w = (u32)f2b(b.z) | ((u32)f2b(b.w) << 16);
        *(uint4*)(dst + off) = r;
        return;
    }

    // ---- prep + scal for batch b (16 waves) ----
    const int b    = blk;
    const int wave = tid >> 6, lane = tid & 63;
    __shared__ float s_hts, s_hi, s_ti, s_is;
    __shared__ float s_part[16];

    const float* hp = emb + (size_t)pair[2*b+0]*D_;
    const float* tp = emb + (size_t)pair[2*b+1]*D_;
    float2 hv = *(const float2*)(hp + 2*lane);
    float2 tv = *(const float2*)(tp + 2*lane);
    float2 uv = *(const float2*)(eu + 2*lane);

    if (wave == 0) {
        float dht = hv.x*tv.x + hv.y*tv.y;
        float dhh = hv.x*hv.x + hv.y*hv.y;
        float dtt = tv.x*tv.x + tv.y*tv.y;
        #pragma unroll
        for (int o = 32; o > 0; o >>= 1) {
            dht += __shfl_xor(dht, o);
            dhh += __shfl_xor(dhh, o);
            dtt += __shfl_xor(dtt, o);
        }
        if (lane == 0) {
            float hn = 1.f / fmaxf(sqrtf(dhh), EPS_);
            float tn = 1.f / fmaxf(sqrtf(dtt), EPS_);
            s_hts = dht*hn*tn;
            s_hi  = hn;
            s_ti  = tn;
        }
    }
    // softmax denominator: 2 relset rows per wave
    float accs = 0.f;
    const float eb = eub[0];
    #pragma unroll
    for (int k = 0; k < 2; ++k) {
        const int r = wave*2 + k;
        const float* ep = emb + (size_t)relset[b*R_+r]*D_;
        float2 ev = *(const float2*)(ep + 2*lane);
        float du = ev.x*uv.x + ev.y*uv.y;
        #pragma unroll
        for (int o = 32; o > 0; o >>= 1) du += __shfl_xor(du, o);
        accs += __expf(du + eb);
    }
    if (lane == 0) s_part[wave] = accs;
    __syncthreads();
    if (tid == 0) {
        float s = 0.f;
        #pragma unroll
        for (int w = 0; w < 16; ++w) s += s_part[w];
        s_is = 1.f/s;
    }
    __syncthreads();

    const float hi = s_hi, ti = s_ti, ht = s_hts, is = s_is;

    for (int pp = wave; pp < P_; pp += 16) {
        const int bp = b*P_ + pp;
        const float* e1 = emb + (size_t)path[3*bp+0]*D_;
        const float* e2 = emb + (size_t)path[3*bp+1]*D_;
        const float* e3 = emb + (size_t)path[3*bp+2]*D_;
        float2 v1 = *(const float2*)(e1 + 2*lane);
        float2 v2 = *(const float2*)(e2 + 2*lane);
        float2 v3 = *(const float2*)(e3 + 2*lane);
        float d1h = v1.x*hv.x + v1.y*hv.y;
        float d1t = v1.x*tv.x + v1.y*tv.y;
        float n1  = v1.x*v1.x + v1.y*v1.y;
        float d2h = v2.x*hv.x + v2.y*hv.y;
        float d2t = v2.x*tv.x + v2.y*tv.y;
        float n2  = v2.x*v2.x + v2.y*v2.y;
        float u1 = v1.x*uv.x + v1.y*uv.y;
        float u2 = v2.x*uv.x + v2.y*uv.y;
        float u3 = v3.x*uv.x + v3.y*uv.y;
        #pragma unroll
        for (int o = 32; o > 0; o >>= 1) {
            d1h += __shfl_xor(d1h,o); d1t += __shfl_xor(d1t,o); n1 += __shfl_xor(n1,o);
            d2h += __shfl_xor(d2h,o); d2t += __shfl_xor(d2t,o); n2 += __shfl_xor(n2,o);
            u1  += __shfl_xor(u1,o);  u2  += __shfl_xor(u2,o);  u3 += __shfl_xor(u3,o);
        }
        if (lane == 0) {
            float n1i = 1.f / fmaxf(sqrtf(n1), EPS_);
            float n2i = 1.f / fmaxf(sqrtf(n2), EPS_);
            float se1 = 0.5f*(d1h*hi + d1t*ti)*n1i;
            float se2 = 0.5f*(d2h*hi + d2t*ti)*n2i;
            float sr0 = 0.5f*(ht  + se1);
            float sr1 = 0.5f*(se1 + se2);
            float sr2 = 0.5f*(ht  + se2);
            sd[3*bp+0] = (1.f - sr0)*0.5f;
            sd[3*bp+1] = (1.f - sr1)*0.5f;
            sd[3*bp+2] = (1.f - sr2)*0.5f;
            se[3*bp+0] = expf(u1 + eb)*is;
            se[3*bp+1] = expf(u2 + eb)*is;
            se[3*bp+2] = expf(u3 + eb)*is;
        }
    }
}

// ---------------- K2: fused cost pipeline, MFMA bf16 ----------------
__global__ __launch_bounds__(256,2) void k_cost(
    const int* __restrict__ path, const float* __restrict__ emb,
    const u16* __restrict__ wdb, const float* __restrict__ bd,
    const u16* __restrict__ web, const float* __restrict__ be,
    const u16* __restrict__ wpb, const float* __restrict__ bp,
    const float* __restrict__ sdg, const float* __restrict__ seg,
    u16* __restrict__ relb)
{
    __shared__ u16   Xs[64*128];
    __shared__ float sdS[64], seS[64];
    __shared__ int   pS[64];
    const int tid  = threadIdx.x;
    const int base = blockIdx.x * 64;

    if (tid < 64) {
        pS[tid]  = path[base + tid];
        sdS[tid] = sdg[base + tid];
        seS[tid] = seg[base + tid];
    }
    __syncthreads();

    #pragma unroll
    for (int i = 0; i < 4; ++i) {
        int gid = i*256 + tid;
        int r = gid >> 4, g = gid & 15;
        const float* sp = emb + (size_t)pS[r]*128 + g*8;
        float4 f0 = *(const float4*)sp;
        float4 f1 = *(const float4*)(sp + 4);
        bf16x8 v = pack8(f0.x,f0.y,f0.z,f0.w, f1.x,f1.y,f1.z,f1.w);
        *(uint4*)(&Xs[r*128 + ((g ^ (r & 7)) << 3)]) = __builtin_bit_cast(uint4, v);
    }
    __syncthreads();

    const int wave = tid >> 6, lane = tid & 63;
    const int lrow = lane & 15, lk8 = lane >> 4;
    const int wn = wave;

    f32x4 accD[4][2], accE[4][2];
    #pragma unroll
    for (int m = 0; m < 4; ++m)
        #pragma unroll
        for (int n = 0; n < 2; ++n) { accD[m][n] = (f32x4){0,0,0,0}; accE[m][n] = (f32x4){0,0,0,0}; }

    #pragma unroll
    for (int ks = 0; ks < 4; ++ks) {
        const int gk = ks*4 + lk8;
        bf16x8 a[4];
        #pragma unroll
        for (int mt = 0; mt < 4; ++mt) a[mt] = ldA(Xs, mt*16 + lrow, gk);
        #pragma unroll
        for (int nt = 0; nt < 2; ++nt) {
            const int n = wn*32 + nt*16 + lrow;
            bf16x8 bD = ldg8(wdb + n*128 + gk*8);
            bf16x8 bE = ldg8(web + n*128 + gk*8);
            #pragma unroll
            for (int mt = 0; mt < 4; ++mt) {
                accD[mt][nt] = __builtin_amdgcn_mfma_f32_16x16x32_bf16(a[mt], bD, accD[mt][nt], 0,0,0);
                accE[mt][nt] = __builtin_amdgcn_mfma_f32_16x16x32_bf16(a[mt], bE, accE[mt][nt], 0,0,0);
            }
        }
    }
    __syncthreads();

    #pragma unroll
    for (int nt = 0; nt < 2; ++nt) {
        const int col = wn*32 + nt*16 + lrow;
        const float bde = bd[col] + be[col];
        #pragma unroll
        for (int mt = 0; mt < 4; ++mt) {
            #pragma unroll
            for (int rr = 0; rr < 4; ++rr) {
                const int row = mt*16 + lk8*4 + rr;
                const int sl  = swz_slot(row, col);
                float relv = b2f(Xs[sl]);
                float c = sdS[row]*accD[mt][nt][rr] + seS[row]*accE[mt][nt][rr] + bde;
                Xs[sl] = f2b(relv - 1e-3f*fmaxf(c, 0.f));
            }
        }
    }
    __syncthreads();

    f32x4 accP[4][2];
    #pragma unroll
    for (int m = 0; m < 4; ++m)
        #pragma unroll
        for (int n = 0; n < 2; ++n) accP[m][n] = (f32x4){0,0,0,0};
    #pragma unroll
    for (int ks = 0; ks < 4; ++ks) {
        const int gk = ks*4 + lk8;
        bf16x8 a[4];
        #pragma unroll
        for (int mt = 0; mt < 4; ++mt) a[mt] = ldA(Xs, mt*16 + lrow, gk);
        #pragma unroll
        for (int nt = 0; nt < 2; ++nt) {
            const int n = wn*32 + nt*16 + lrow;
            bf16x8 bP = ldg8(wpb + n*128 + gk*8);
            #pragma unroll
            for (int mt = 0; mt < 4; ++mt)
                accP[mt][nt] = __builtin_amdgcn_mfma_f32_16x16x32_bf16(a[mt], bP, accP[mt][nt], 0,0,0);
        }
    }

    #pragma unroll
    for (int nt = 0; nt < 2; ++nt) {
        const int col = wn*32 + nt*16 + lrow;
        const float bpv = bp[col];
        #pragma unroll
        for (int mt = 0; mt < 4; ++mt) {
            #pragma unroll
            for (int rr = 0; rr < 4; ++rr) {
                const int row  = mt*16 + lk8*4 + rr;
                const int grow = base + row;
                const int tt   = grow - (grow/3)*3;
                const int bprow= grow/3;
                relb[((size_t)tt*NBP + bprow)*128 + col] = f2b(accP[mt][nt][rr] + bpv);
            }
        }
    }
}

// ---- async DMA stage of one 64x128 bf16 x-tile into swizzled LDS ----
// linear LDS dest (lane-ordered), inverse-swizzled global source (rule #21)
__device__ __forceinline__ void stage_x(const u16* __restrict__ xsl, int bp0,
                                        u16* __restrict__ Xbuf, int tid)
{
    #pragma unroll
    for (int is = 0; is < 2; ++is) {
        const int G  = is*512 + tid;          // granule 0..1023 (16B each)
        const int r  = G >> 4, gs = G & 15;
        const u16* src = xsl + (size_t)(bp0 + r)*128 + ((gs ^ (r & 7)) << 3);
        __builtin_amdgcn_global_load_lds(
            (const __attribute__((address_space(1))) void*)src,
            (__attribute__((address_space(3))) void*)(Xbuf + (size_t)G*8),
            16, 0, 0);
    }
}

// ---- GRU gate GEMMs for one step (reads LDS only; weights in regs) ----
template<bool HAS_H>
__device__ __forceinline__ void gru_gates(
    const u16* __restrict__ Xbuf, const u16* __restrict__ Hs,
    int lrow, int lk8,
    const bf16x8* wR, const bf16x8* wZ, const bf16x8* wI,
    const bf16x8* vR, const bf16x8* vZ, const bf16x8* vH,
    f32x4* aR, f32x4* aZ, f32x4* aI, f32x4* aH)
{
    #pragma unroll
    for (int m = 0; m < 4; ++m) {
        aR[m] = (f32x4){0,0,0,0}; aZ[m] = (f32x4){0,0,0,0};
        aI[m] = (f32x4){0,0,0,0}; aH[m] = (f32x4){0,0,0,0};
    }
    #pragma unroll
    for (int ks = 0; ks < 4; ++ks) {
        const int gk = ks*4 + lk8;
        bf16x8 ax[4];
        #pragma unroll
        for (int mt = 0; mt < 4; ++mt) ax[mt] = ldA(Xbuf, mt*16 + lrow, gk);
        #pragma unroll
        for (int mt = 0; mt < 4; ++mt) {
            aR[mt] = __builtin_amdgcn_mfma_f32_16x16x32_bf16(ax[mt], wR[ks], aR[mt], 0,0,0);
            aZ[mt] = __builtin_amdgcn_mfma_f32_16x16x32_bf16(ax[mt], wZ[ks], aZ[mt], 0,0,0);
            aI[mt] = __builtin_amdgcn_mfma_f32_16x16x32_bf16(ax[mt], wI[ks], aI[mt], 0,0,0);
        }
        if (HAS_H) {
            bf16x8 ah[4];
            #pragma unroll
            for (int mt = 0; mt < 4; ++mt) ah[mt] = ldA(Hs, mt*16 + lrow, gk);
            #pragma unroll
            for (int mt = 0; mt < 4; ++mt) {
                aR[mt] = __builtin_amdgcn_mfma_f32_16x16x32_bf16(ah[mt], vR[ks], aR[mt], 0,0,0);
                aZ[mt] = __builtin_amdgcn_mfma_f32_16x16x32_bf16(ah[mt], vZ[ks], aZ[mt], 0,0,0);
                aH[mt] = __builtin_amdgcn_mfma_f32_16x16x32_bf16(ah[mt], vH[ks], aH[mt], 0,0,0);
            }
        }
    }
}

// ---------------- K3: full GRU, LDS-staged x, register weights ----------------
// 512 thr (8 waves), 64 rows/block, grid 256; each wave owns a 16-col strip.
__global__ __launch_bounds__(512,2) void k_gru3(
    const u16* __restrict__ relb,    // [3][16384][128] bf16, t-major
    const u16* __restrict__ wib, const u16* __restrict__ whb,
    const float* __restrict__ bih, const float* __restrict__ bhh,
    float* __restrict__ out)
{
    __shared__ u16 X0[64*128];        // 16 KB
    __shared__ u16 X1[64*128];        // 16 KB
    __shared__ u16 Hs[64*128];        // 16 KB
    const int tid  = threadIdx.x;
    const int bp0  = blockIdx.x * 64;
    const int wave = tid >> 6, lane = tid & 63;
    const int lrow = lane & 15, lk8 = lane >> 4;
    const int col  = wave*16 + lrow;

    // ---- weight fragments in registers (loaded once) ----
    bf16x8 wR[4], wZ[4], wI[4], vR[4], vZ[4], vH[4];
    #pragma unroll
    for (int ks = 0; ks < 4; ++ks) {
        const int gk = ks*4 + lk8;
        wR[ks] = ldg8(wib +             col*128 + gk*8);
        wZ[ks] = ldg8(wib + 16384     + col*128 + gk*8);
        wI[ks] = ldg8(wib + 2*16384   + col*128 + gk*8);
        vR[ks] = ldg8(whb +             col*128 + gk*8);
        vZ[ks] = ldg8(whb + 16384     + col*128 + gk*8);
        vH[ks] = ldg8(whb + 2*16384   + col*128 + gk*8);
    }
    const float brv = bih[col]       + bhh[col];
    const float bzv = bih[128 + col] + bhh[128 + col];
    const float biN = bih[256 + col];
    const float bhN = bhh[256 + col];

    float hreg[4][4];
    #pragma unroll
    for (int m = 0; m < 4; ++m)
        #pragma unroll
        for (int r = 0; r < 4; ++r) hreg[m][r] = 0.f;

    f32x4 aR[4], aZ[4], aI[4], aH[4];

    // prologue: stage t0 and t1 tiles (async DMA, in flight together)
    stage_x(relb,                      bp0, X0, tid);
    stage_x(relb + (size_t)NBP*128,    bp0, X1, tid);
    __syncthreads();                  // B1: X0,X1 ready (single cold-latency hit)

    // ---- t = 0 (h = 0: x-side only) ----
    gru_gates<false>(X0, Hs, lrow, lk8, wR, wZ, wI, vR, vZ, vH, aR, aZ, aI, aH);
    #pragma unroll
    for (int mt = 0; mt < 4; ++mt)
        #pragma unroll
        for (int rr = 0; rr < 4; ++rr) {
            const int row = mt*16 + lk8*4 + rr;
            float rv = sigm_f(aR[mt][rr] + brv);
            float zv = sigm_f(aZ[mt][rr] + bzv);
            float nn = tanh_f(aI[mt][rr] + biN + rv*bhN);
            float h2 = (1.f - zv)*nn;
            hreg[mt][rr] = h2;
            Hs[swz_slot(row, col)] = f2b(h2);
        }
    __syncthreads();                  // B2: Hs(t0) visible; X0 free

    // ---- t = 1 ----
    stage_x(relb + (size_t)2*NBP*128,  bp0, X0, tid);   // prefetch t2 (overlaps gates)
    gru_gates<true>(X1, Hs, lrow, lk8, wR, wZ, wI, vR, vZ, vH, aR, aZ, aI, aH);
    __syncthreads();                  // B3: all Hs reads done; t2 tile drained (overlapped)
    #pragma unroll
    for (int mt = 0; mt < 4; ++mt)
        #pragma unroll
        for (int rr = 0; rr < 4; ++rr) {
            const int row = mt*16 + lk8*4 + rr;
            float rv = sigm_f(aR[mt][rr] + brv);
            float zv = sigm_f(aZ[mt][rr] + bzv);
            float hn = aH[mt][rr] + bhN;
            float nn = tanh_f(aI[mt][rr] + biN + rv*hn);
            float h2 = (1.f - zv)*nn + zv*hreg[mt][rr];
            hreg[mt][rr] = h2;
            Hs[swz_slot(row, col)] = f2b(h2);
        }
    __syncthreads();                  // B4: Hs(t1) visible

    // ---- t = 2 ----
    gru_gates<true>(X0, Hs, lrow, lk8, wR, wZ, wI, vR, vZ, vH, aR, aZ, aI, aH);
    #pragma unroll
    for (int mt = 0; mt < 4; ++mt)
        #pragma unroll
        for (int rr = 0; rr < 4; ++rr) {
            const int row = mt*16 + lk8*4 + rr;
            float rv = sigm_f(aR[mt][rr] + brv);
            float zv = sigm_f(aZ[mt][rr] + bzv);
            float hn = aH[mt][rr] + bhN;
            float nn = tanh_f(aI[mt][rr] + biN + rv*hn);
            float h2 = (1.f - zv)*nn + zv*hreg[mt][rr];
            out[(size_t)(bp0 + row)*128 + col] = h2;
        }
}

extern "C" void kernel_launch(void* const* d_in, const int* in_sizes, int n_in,
                              void* d_out, int out_size, void* d_ws, size_t ws_size,
                              hipStream_t stream)
{
    const int*   path   = (const int*)d_in[0];
    const int*   pair   = (const int*)d_in[1];
    const int*   relset = (const int*)d_in[2];
    const float* emb    = (const float*)d_in[3];
    const float* wd     = (const float*)d_in[4];
    const float* bd     = (const float*)d_in[5];
    const float* we     = (const float*)d_in[6];
    const float* be     = (const float*)d_in[7];
    const float* wp     = (const float*)d_in[8];
    const float* bp     = (const float*)d_in[9];
    const float* eu     = (const float*)d_in[10];
    const float* eub    = (const float*)d_in[11];
    const float* wih    = (const float*)d_in[12];
    const float* whh    = (const float*)d_in[13];
    const float* bih    = (const float*)d_in[14];
    const float* bhh    = (const float*)d_in[15];
    float* out = (float*)d_out;
    float* ws  = (float*)d_ws;

    // workspace (float offsets), total ~12.7 MB
    float* sdg  = ws;                      // 49152
    float* seg  = ws + NROW;               // 49152 -> ends 98304
    u16*   relb = (u16*)(ws + 98304);      // 3*16384*128 bf16 -> ends 3244032
    u16*   wdb  = (u16*)(ws + 3244032);    // -> 3252224
    u16*   web  = (u16*)(ws + 3252224);    // -> 3260416
    u16*   wpb  = (u16*)(ws + 3260416);    // -> 3268608
    u16*   wib  = (u16*)(ws + 3268608);    // -> 3293184
    u16*   whb  = (u16*)(ws + 3293184);    // -> 3317760 (12.7 MB)

    k_fuse0<<<B_ + 18, 1024, 0, stream>>>(pair, relset, path, emb, eu, eub,
                                          wd, we, wp, wih, whh,
                                          wdb, web, wpb, wib, whb, sdg, seg);
    k_cost <<<NROW/64,  256, 0, stream>>>(path, emb, wdb, bd, web, be, wpb, bp,
                                          sdg, seg, relb);
    k_gru3 <<<NBP/64,   512, 0, stream>>>(relb, wib, whb, bih, bhh, out);
}